// Round 7
// baseline (309.627 us; speedup 1.0000x reference)
//
#include <hip/hip_runtime.h>
#include <math.h>

#define N_NODES 100000
#define N_EDGES 1000000
#define NGRAPH 256

#define NBUCK 196          // ceil(100000 / 512)
#define BUCKN 512
#define EPB1 1024          // edges per block, both edge passes (4/thread)
#define NBIN1 ((N_EDGES + EPB1 - 1) / EPB1)              // 977
#define NBOUND_BLOCKS ((N_NODES + 255) / 256)            // 391
#define WINCAP 10240       // fixed csr window per bucket
#define DUMMY ((unsigned)N_NODES)   // pad col -> node with hs == 0
#define H0_BLOCKS ((N_NODES / 16 + 3) / 4)               // 1563

typedef unsigned short ushort_t;
typedef __attribute__((ext_vector_type(2))) float floatx2;

__device__ __forceinline__ ushort_t f2bf(float f) {   // round-to-nearest-even
    unsigned u = __float_as_uint(f);
    u += 0x7fffu + ((u >> 16) & 1u);
    return (ushort_t)(u >> 16);
}
__device__ __forceinline__ float bf2f(ushort_t u) {
    return __uint_as_float(((unsigned)u) << 16);
}
__device__ __forceinline__ float bf_lo(unsigned u) {
    return __uint_as_float(u << 16);
}
__device__ __forceinline__ float bf_hi(unsigned u) {
    return __uint_as_float(u & 0xffff0000u);
}
__device__ __forceinline__ unsigned pack2(float hi, float lo) {
    return ((unsigned)f2bf(hi) << 16) | (unsigned)f2bf(lo);
}
// fp8 e4m3 (OCP) HW converts, gfx950
__device__ __forceinline__ floatx2 fp8x2_lo(unsigned u) {       // bytes 0,1
    return __builtin_amdgcn_cvt_pk_f32_fp8(u, false);
}
__device__ __forceinline__ floatx2 fp8x2_hi(unsigned u) {       // bytes 2,3
    return __builtin_amdgcn_cvt_pk_f32_fp8(u, true);
}
__device__ __forceinline__ ushort_t f32_fp8x2(float a, float b) {
    return (ushort_t)(__builtin_amdgcn_cvt_pk_fp8_f32(a, b, 0u, false) & 0xffffu);
}
__device__ __forceinline__ unsigned char f32_fp8(float a) {
    return (unsigned char)(__builtin_amdgcn_cvt_pk_fp8_f32(a, 0.f, 0u, false) & 0xffu);
}

using frag_ab = __attribute__((ext_vector_type(8))) short;
using frag_cd = __attribute__((ext_vector_type(4))) float;

// ------ Pass 1: blocks [0,NBIN1) count row-degrees; rest do graph bounds ----
__global__ __launch_bounds__(256) void k_deg_bounds(const int* __restrict__ row,
        const int* __restrict__ batch, int* __restrict__ gbound,
        int* __restrict__ deg) {
    int t = threadIdx.x;
    if (blockIdx.x < NBIN1) {
        int e0 = blockIdx.x * EPB1 + t * 4;
        if (e0 + 4 <= N_EDGES) {
            int4 r4 = *(const int4*)(row + e0);
            atomicAdd(&deg[r4.x], 1);
            atomicAdd(&deg[r4.y], 1);
            atomicAdd(&deg[r4.z], 1);
            atomicAdd(&deg[r4.w], 1);
        } else {
            for (int e = e0; e < N_EDGES; ++e) atomicAdd(&deg[row[e]], 1);
        }
        return;
    }
    int n = (blockIdx.x - NBIN1) * 256 + t;
    if (n >= N_NODES) return;
    int b = batch[n];
    int prev = (n == 0) ? -1 : batch[n - 1];
    for (int g = prev + 1; g <= b; ++g) gbound[g] = n;
    if (n == N_NODES - 1) {
        for (int g = b + 1; g <= NGRAPH; ++g) gbound[g] = N_NODES;
    }
}

// ------ S2 fused: blocks [0,NBUCK) scan deg -> CSR starts; rest compute h0 --
// Bucket half: pad-to-4 counts, LDS exclusive scan over 512 nodes, DUMMY pads.
__global__ __launch_bounds__(256) void k_build_h0(
        int* __restrict__ start, int* __restrict__ counts, float* __restrict__ dinv,
        unsigned* __restrict__ csr4,
        const float* __restrict__ x, const float* __restrict__ W,
        const float* __restrict__ bias, const int* __restrict__ deg,
        ushort_t* __restrict__ h0b, unsigned char* __restrict__ h0s) {
    __shared__ int sc[256];
    int b = blockIdx.x, t = threadIdx.x;
    if (b < NBUCK) {
        int node0 = b * BUCKN;
        int nn = min(BUCKN, N_NODES - node0);
        int ebase = b * WINCAP;
        int n0 = node0 + 2 * t, n1 = n0 + 1;
        int c0 = (2 * t < nn) ? deg[n0] : 0;
        int c1 = (2 * t + 1 < nn) ? deg[n1] : 0;
        int p0 = (c0 + 3) & ~3, p1 = (c1 + 3) & ~3;
        int ps = p0 + p1;
        sc[t] = ps; __syncthreads();
        for (int off = 1; off < 256; off <<= 1) {
            int v = (t >= off) ? sc[t - off] : 0;
            __syncthreads();
            sc[t] += v;
            __syncthreads();
        }
        int ex = sc[t] - ps;
        if (2 * t < nn) {
            int st = ebase + ex;
            start[n0] = st; counts[n0] = p0;              // PADDED count for hop
            dinv[n0] = rsqrtf((float)(c0 + 1));           // true degree for norm
            for (int k = c0; k < p0; ++k) csr4[st + k] = DUMMY;
        }
        if (2 * t + 1 < nn) {
            int st = ebase + ex + p0;
            start[n1] = st; counts[n1] = p1;
            dinv[n1] = rsqrtf((float)(c1 + 1));
            for (int k = c1; k < p1; ++k) csr4[st + k] = DUMMY;
        }
    } else {
        // ---------------- h0 = x @ W_sgc + b_sgc (bf16 + fp8) ---------------
        int wid = ((b - NBUCK) * 256 + t) >> 6;
        if (wid >= N_NODES / 16) return;
        int lane = t & 63;
        int row0 = wid * 16;
        int m = lane & 15, q = lane >> 4;

        frag_ab bfr[2][4];
#pragma unroll
        for (int ks = 0; ks < 2; ++ks)
#pragma unroll
            for (int nt = 0; nt < 4; ++nt)
#pragma unroll
                for (int j = 0; j < 8; ++j)
                    bfr[ks][nt][j] = (short)f2bf(W[(ks * 32 + q * 8 + j) * 64 + nt * 16 + m]);

        frag_ab afr[2];
#pragma unroll
        for (int ks = 0; ks < 2; ++ks) {
            const float4* xp = (const float4*)(x + (size_t)(row0 + m) * 64 + ks * 32 + q * 8);
            float4 v0 = xp[0], v1 = xp[1];
            afr[ks][0] = (short)f2bf(v0.x); afr[ks][1] = (short)f2bf(v0.y);
            afr[ks][2] = (short)f2bf(v0.z); afr[ks][3] = (short)f2bf(v0.w);
            afr[ks][4] = (short)f2bf(v1.x); afr[ks][5] = (short)f2bf(v1.y);
            afr[ks][6] = (short)f2bf(v1.z); afr[ks][7] = (short)f2bf(v1.w);
        }

        frag_cd acc[4];
#pragma unroll
        for (int nt = 0; nt < 4; ++nt) acc[nt] = (frag_cd){0.f, 0.f, 0.f, 0.f};
#pragma unroll
        for (int ks = 0; ks < 2; ++ks)
#pragma unroll
            for (int nt = 0; nt < 4; ++nt)
                acc[nt] = __builtin_amdgcn_mfma_f32_16x16x32_bf16(afr[ks], bfr[ks][nt], acc[nt], 0, 0, 0);

        float dv[4];
#pragma unroll
        for (int r = 0; r < 4; ++r)
            dv[r] = rsqrtf((float)(deg[row0 + q * 4 + r] + 1));   // same value bucket half writes

#pragma unroll
        for (int nt = 0; nt < 4; ++nt) {
            int cc = nt * 16 + m;
            float bl = bias[cc];
#pragma unroll
            for (int r = 0; r < 4; ++r) {
                int rr = row0 + q * 4 + r;
                float hv = acc[nt][r] + bl;
                h0b[(size_t)rr * 64 + cc] = f2bf(hv);
                h0s[(size_t)rr * 64 + cc] = f32_fp8(hv * dv[r]);   // byte store
            }
        }
        if (wid == 0) h0s[(size_t)N_NODES * 64 + lane] = 0;   // dummy row = 0
    }
}

// ------ Pass 2: scatter cols directly into final CSR (order-free) -----------
__global__ __launch_bounds__(256) void k_scatter(const int* __restrict__ row,
        const int* __restrict__ col, const int* __restrict__ start,
        int* __restrict__ cur, unsigned* __restrict__ csr4) {
    int e0 = blockIdx.x * EPB1 + (int)threadIdx.x * 4;
    if (e0 + 4 <= N_EDGES) {
        int4 r4 = *(const int4*)(row + e0);
        int4 c4 = *(const int4*)(col + e0);
        int p0 = atomicAdd(&cur[r4.x], 1);
        int p1 = atomicAdd(&cur[r4.y], 1);
        int p2 = atomicAdd(&cur[r4.z], 1);
        int p3 = atomicAdd(&cur[r4.w], 1);
        csr4[start[r4.x] + p0] = (unsigned)c4.x;
        csr4[start[r4.y] + p1] = (unsigned)c4.y;
        csr4[start[r4.z] + p2] = (unsigned)c4.z;
        csr4[start[r4.w] + p3] = (unsigned)c4.w;
    } else {
        for (int e = e0; e < N_EDGES; ++e) {
            int r = row[e];
            int p = atomicAdd(&cur[r], 1);
            csr4[start[r] + p] = (unsigned)col[e];
        }
    }
}

// ---- hop inner sum: 16 lanes/node (4 nodes/wave), dword fp8 gathers --------
// lane l (0..15) handles features 4l..4l+3 (one dword = 4 fp8).
// Software-pipelined: next CSR uint4 issued before current group's gathers.
__device__ __forceinline__ void hop_sum4(int node, int l,
        const unsigned* __restrict__ hs_in, const int* __restrict__ start,
        const int* __restrict__ counts, const unsigned* __restrict__ csr4,
        float& a0, float& a1, float& a2, float& a3) {
    unsigned su = hs_in[node * 16 + l];            // self-loop term (hs form)
    floatx2 slo = fp8x2_lo(su), shi = fp8x2_hi(su);
    a0 = slo.x; a1 = slo.y; a2 = shi.x; a3 = shi.y;
    int st = start[node], cnt = counts[node];      // cnt % 4 == 0, st 16B-aligned
    if (cnt <= 0) return;
    uint4 cc = *(const uint4*)(csr4 + st);         // prologue group
    for (int j = 4; ; j += 4) {
        bool more = j < cnt;
        uint4 nx;
        if (more) nx = *(const uint4*)(csr4 + st + j);   // prefetch next group
        unsigned w0 = hs_in[cc.x * 16 + l];
        unsigned w1 = hs_in[cc.y * 16 + l];
        unsigned w2 = hs_in[cc.z * 16 + l];
        unsigned w3 = hs_in[cc.w * 16 + l];
        floatx2 l0 = fp8x2_lo(w0), h0 = fp8x2_hi(w0);
        floatx2 l1 = fp8x2_lo(w1), h1 = fp8x2_hi(w1);
        floatx2 l2 = fp8x2_lo(w2), h2 = fp8x2_hi(w2);
        floatx2 l3 = fp8x2_lo(w3), h3 = fp8x2_hi(w3);
        a0 += (l0.x + l1.x) + (l2.x + l3.x);
        a1 += (l0.y + l1.y) + (l2.y + l3.y);
        a2 += (h0.x + h1.x) + (h2.x + h3.x);
        a3 += (h0.y + h1.y) + (h2.y + h3.y);
        if (!more) break;
        cc = nx;
    }
}

// intermediate hop: residual from hs0 (fp8), writes fp8 hs_out (dword/lane):
//   hs_{k+1} = dinv * h_{k+1} = 0.5*di^2*S + 0.5*hs0
__global__ void k_hop(const unsigned* __restrict__ hs_in, const unsigned* __restrict__ hs0,
                      const float* __restrict__ dinv, const int* __restrict__ start,
                      const int* __restrict__ counts, const unsigned* __restrict__ csr4,
                      unsigned* __restrict__ hs_out) {
    int node = blockIdx.x * 16 + ((int)threadIdx.x >> 4);   // N_NODES % 16 == 0
    int l = threadIdx.x & 15;
    float a0, a1, a2, a3;
    hop_sum4(node, l, hs_in, start, counts, csr4, a0, a1, a2, a3);
    float di = dinv[node];
    float c = 0.5f * di * di;
    unsigned ru = hs0[node * 16 + l];
    floatx2 rlo = fp8x2_lo(ru), rhi = fp8x2_hi(ru);
    ushort_t lo = f32_fp8x2(c * a0 + 0.5f * rlo.x, c * a1 + 0.5f * rlo.y);
    ushort_t hi = f32_fp8x2(c * a2 + 0.5f * rhi.x, c * a3 + 0.5f * rhi.y);
    hs_out[node * 16 + l] = (unsigned)lo | ((unsigned)hi << 16);
    if (blockIdx.x == 0 && threadIdx.x < 16)
        hs_out[N_NODES * 16 + threadIdx.x] = 0;             // dummy row = 0
}

// final hop: bf16 h out (relu, residual from bf16 h0b) + attention gate
__global__ void k_hop_final(const unsigned* __restrict__ hs_in, const uint2* __restrict__ h0b2,
                            const float* __restrict__ dinv, const int* __restrict__ start,
                            const int* __restrict__ counts, const unsigned* __restrict__ csr4,
                            const float* __restrict__ w_att, const float* __restrict__ b_att,
                            uint2* __restrict__ h_out2, float* __restrict__ v_raw) {
    int node = blockIdx.x * 16 + ((int)threadIdx.x >> 4);
    int l = threadIdx.x & 15;
    float a0, a1, a2, a3;
    hop_sum4(node, l, hs_in, start, counts, csr4, a0, a1, a2, a3);
    float cdi = 0.5f * dinv[node];
    uint2 u = h0b2[node * 16 + l];
    float h0v = fmaxf(cdi * a0 + 0.5f * bf_lo(u.x), 0.f);
    float h1v = fmaxf(cdi * a1 + 0.5f * bf_hi(u.x), 0.f);
    float h2v = fmaxf(cdi * a2 + 0.5f * bf_lo(u.y), 0.f);
    float h3v = fmaxf(cdi * a3 + 0.5f * bf_hi(u.y), 0.f);
    uint2 o; o.x = pack2(h1v, h0v); o.y = pack2(h3v, h2v);
    h_out2[node * 16 + l] = o;
    float4 wa = *(const float4*)(w_att + 4 * l);
    float pp = (h0v * wa.x + h1v * wa.y) + (h2v * wa.z + h3v * wa.w);
#pragma unroll
    for (int off = 8; off >= 1; off >>= 1) pp += __shfl_xor(pp, off, 64);
    if (l == 0) {
        v_raw[node] = 1.f / (1.f + expf(-(pp + b_att[0])));
    }
}

// ---------------- readout + MLP head, one block per graph ----------------
__global__ void k_readout_mlp(const ushort_t* __restrict__ hb, const float* __restrict__ v_raw,
        const int* __restrict__ gbound,
        const float* __restrict__ W1, const float* __restrict__ b1,
        const float* __restrict__ W2, const float* __restrict__ b2,
        const float* __restrict__ W3, const float* __restrict__ b3,
        float* __restrict__ out) {
    int g = blockIdx.x, t = threadIdx.x;
    int s = gbound[g], e = gbound[g + 1];
    __shared__ float red[256];

    float m = -3.402823466e38f;
    for (int n = s + t; n < e; n += 256) m = fmaxf(m, v_raw[n]);
    red[t] = m; __syncthreads();
    for (int off = 128; off >= 1; off >>= 1) {
        if (t < off) red[t] = fmaxf(red[t], red[t + off]);
        __syncthreads();
    }
    float vmax = red[0]; __syncthreads();

    float ss = 0.f;
    for (int n = s + t; n < e; n += 256) ss += expf(v_raw[n] - vmax);
    red[t] = ss; __syncthreads();
    for (int off = 128; off >= 1; off >>= 1) {
        if (t < off) red[t] += red[t + off];
        __syncthreads();
    }
    float inv = 1.f / (red[0] + 1e-16f);
    __syncthreads();

    int wv = t >> 6, lane = t & 63;
    float gm = -3.402823466e38f, gs = 0.f;
    for (int n = s + wv; n < e; n += 4) {
        float hv = bf2f(hb[(size_t)n * 64 + lane]);
        float vn = expf(v_raw[n] - vmax) * inv;
        gm = fmaxf(gm, hv);
        gs += vn * hv;
    }
    __shared__ float pm[4][64], ps[4][64];
    pm[wv][lane] = gm; ps[wv][lane] = gs;
    __syncthreads();

    __shared__ float z[128];
    if (t < 64) {
        z[t] = fmaxf(fmaxf(pm[0][t], pm[1][t]), fmaxf(pm[2][t], pm[3][t]));
        z[64 + t] = ps[0][t] + ps[1][t] + ps[2][t] + ps[3][t];
    }
    __syncthreads();

    __shared__ float z1[64];
    if (t < 64) {
        float a = b1[t];
#pragma unroll 8
        for (int k = 0; k < 128; ++k) a += z[k] * W1[k * 64 + t];
        z1[t] = fmaxf(a, 0.f);
    }
    __syncthreads();
    __shared__ float z2[32];
    if (t < 32) {
        float a = b2[t];
#pragma unroll 8
        for (int k = 0; k < 64; ++k) a += z1[k] * W2[k * 32 + t];
        z2[t] = fmaxf(a, 0.f);
    }
    __syncthreads();
    __shared__ float z3[8];
    if (t < 8) {
        float a = b3[t];
#pragma unroll
        for (int k = 0; k < 32; ++k) a += z2[k] * W3[k * 8 + t];
        z3[t] = a;
    }
    __syncthreads();
    if (t == 0) {
        float mx = z3[0];
#pragma unroll
        for (int j = 1; j < 8; ++j) mx = fmaxf(mx, z3[j]);
        float se = 0.f;
#pragma unroll
        for (int j = 0; j < 8; ++j) se += expf(z3[j] - mx);
        float lse = mx + logf(se);
#pragma unroll
        for (int j = 0; j < 8; ++j) out[g * 8 + j] = z3[j] - lse;
    }
}

extern "C" void kernel_launch(void* const* d_in, const int* in_sizes, int n_in,
                              void* d_out, int out_size, void* d_ws, size_t ws_size,
                              hipStream_t stream) {
    const float* x     = (const float*)d_in[0];
    const int*   edge  = (const int*)d_in[1];
    const int*   row   = edge;
    const int*   col   = edge + N_EDGES;
    const int*   batch = (const int*)d_in[2];
    const float* W_sgc = (const float*)d_in[3];
    const float* b_sgc = (const float*)d_in[4];
    const float* w_att = (const float*)d_in[5];
    const float* b_att = (const float*)d_in[6];
    const float* W1    = (const float*)d_in[7];
    const float* b1    = (const float*)d_in[8];
    const float* W2    = (const float*)d_in[9];
    const float* b2    = (const float*)d_in[10];
    const float* W3    = (const float*)d_in[11];
    const float* b3    = (const float*)d_in[12];
    float* out = (float*)d_out;

    char* p = (char*)d_ws;
    auto alloc = [&](size_t bytes) {
        char* r = p;
        p += (bytes + 255) & ~(size_t)255;
        return r;
    };
    int*      deg     = (int*)alloc((size_t)N_NODES * 4);        // zeroed below
    int*      cur     = (int*)alloc((size_t)N_NODES * 4);        // zeroed below (adjacent)
    int*      gbound  = (int*)alloc((size_t)(NGRAPH + 1) * 4);
    int*      start   = (int*)alloc((size_t)N_NODES * 4);
    int*      counts  = (int*)alloc((size_t)N_NODES * 4);
    float*    dinv    = (float*)alloc((size_t)N_NODES * 4);
    float*    vraw    = (float*)alloc((size_t)N_NODES * 4);
    ushort_t* h0b     = (ushort_t*)alloc((size_t)N_NODES * 64 * 2);          // bf16
    unsigned char* h0s = (unsigned char*)alloc((size_t)(N_NODES + 1) * 64);  // fp8
    ushort_t* hAs     = (ushort_t*)alloc((size_t)(N_NODES + 1) * 32 * 2);    // fp8
    ushort_t* hBs     = (ushort_t*)alloc((size_t)(N_NODES + 1) * 32 * 2);    // fp8
    ushort_t* hfin    = (ushort_t*)alloc((size_t)N_NODES * 64 * 2);          // bf16 final h
    unsigned* csr4    = (unsigned*)alloc(((size_t)NBUCK * WINCAP + 64) * 4); // fixed windows

    // one memset spans deg (padded to 400128B) + cur (adjacent allocation)
    hipMemsetAsync(deg, 0, (size_t)400128 + (size_t)N_NODES * 4, stream);

    k_deg_bounds<<<NBIN1 + NBOUND_BLOCKS, 256, 0, stream>>>(row, batch, gbound, deg);
    k_build_h0<<<NBUCK + H0_BLOCKS, 256, 0, stream>>>(
        start, counts, dinv, csr4, x, W_sgc, b_sgc, deg, h0b, (unsigned char*)h0s);
    k_scatter<<<NBIN1, 256, 0, stream>>>(row, col, start, cur, csr4);
    k_hop<<<N_NODES / 16, 256, 0, stream>>>((const unsigned*)h0s, (const unsigned*)h0s,
                                            dinv, start, counts, csr4, (unsigned*)hAs);
    k_hop<<<N_NODES / 16, 256, 0, stream>>>((const unsigned*)hAs, (const unsigned*)h0s,
                                            dinv, start, counts, csr4, (unsigned*)hBs);
    k_hop_final<<<N_NODES / 16, 256, 0, stream>>>((const unsigned*)hBs, (const uint2*)h0b,
                                                  dinv, start, counts, csr4,
                                                  w_att, b_att, (uint2*)hfin, vraw);
    k_readout_mlp<<<NGRAPH, 256, 0, stream>>>(hfin, vraw, gbound,
                                              W1, b1, W2, b2, W3, b3, out);
}

// Round 8
// 257.527 us; speedup vs baseline: 1.2023x; 1.2023x over previous
//
#include <hip/hip_runtime.h>
#include <math.h>

#define N_NODES 100000
#define N_EDGES 1000000
#define NGRAPH 256

#define NBUCK 196          // ceil(100000 / 512)
#define BUCKN 512
#define BUCKCAP 8192       // max raw edges/bucket (mean ~5120, ~40 sigma margin)
#define EPB 2048           // edges per bin block (8/thread)
#define NBIN_BLOCKS ((N_EDGES + EPB - 1) / EPB)          // 489
#define NBOUND_BLOCKS ((N_NODES + 255) / 256)            // 391
#define WINCAP 10240       // fixed csr window per bucket
#define DUMMY ((unsigned)N_NODES)   // pad col -> node with hs == 0
#define H0_BLOCKS ((N_NODES / 16 + 3) / 4)               // 1563

typedef unsigned short ushort_t;
typedef __attribute__((ext_vector_type(2))) float floatx2;

__device__ __forceinline__ ushort_t f2bf(float f) {   // round-to-nearest-even
    unsigned u = __float_as_uint(f);
    u += 0x7fffu + ((u >> 16) & 1u);
    return (ushort_t)(u >> 16);
}
__device__ __forceinline__ float bf2f(ushort_t u) {
    return __uint_as_float(((unsigned)u) << 16);
}
__device__ __forceinline__ float bf_lo(unsigned u) {
    return __uint_as_float(u << 16);
}
__device__ __forceinline__ float bf_hi(unsigned u) {
    return __uint_as_float(u & 0xffff0000u);
}
__device__ __forceinline__ unsigned pack2(float hi, float lo) {
    return ((unsigned)f2bf(hi) << 16) | (unsigned)f2bf(lo);
}
// fp8 e4m3 (OCP) HW converts, gfx950
__device__ __forceinline__ floatx2 fp8x2_lo(unsigned u) {       // bytes 0,1
    return __builtin_amdgcn_cvt_pk_f32_fp8(u, false);
}
__device__ __forceinline__ floatx2 fp8x2_hi(unsigned u) {       // bytes 2,3
    return __builtin_amdgcn_cvt_pk_f32_fp8(u, true);
}
__device__ __forceinline__ ushort_t f32_fp8x2(float a, float b) {
    return (ushort_t)(__builtin_amdgcn_cvt_pk_fp8_f32(a, b, 0u, false) & 0xffffu);
}
__device__ __forceinline__ unsigned char f32_fp8(float a) {
    return (unsigned char)(__builtin_amdgcn_cvt_pk_fp8_f32(a, 0.f, 0u, false) & 0xffu);
}

using frag_ab = __attribute__((ext_vector_type(8))) short;
using frag_cd = __attribute__((ext_vector_type(4))) float;

// ------ S1: blocks [0,NBIN_BLOCKS) LDS-staged coalesced bin; rest bounds ----
// Write amplification fix: records are bucket-sorted in LDS, then copied out
// so consecutive lanes hit consecutive slab addresses within each bucket run.
__global__ __launch_bounds__(256) void k_binstage_bounds(const int* __restrict__ row,
        const int* __restrict__ col, int* __restrict__ gcursor,
        unsigned* __restrict__ slab,
        const int* __restrict__ batch, int* __restrict__ gbound,
        int* __restrict__ deg) {
    __shared__ int lcount[NBUCK];
    __shared__ int lbase[NBUCK];       // reserve, then folded dest base
    __shared__ int sexcl[NBUCK];       // block-local exclusive scan
    __shared__ int sc[256];
    __shared__ unsigned staged[EPB];
    __shared__ int sdelta[EPB];
    int t = threadIdx.x;
    if (blockIdx.x >= NBIN_BLOCKS) {
        int n = (blockIdx.x - NBIN_BLOCKS) * 256 + t;
        if (n >= N_NODES) return;
        int b = batch[n];
        int prev = (n == 0) ? -1 : batch[n - 1];
        for (int g = prev + 1; g <= b; ++g) gbound[g] = n;
        if (n == N_NODES - 1) {
            for (int g = b + 1; g <= NGRAPH; ++g) gbound[g] = N_NODES;
        }
        return;
    }
    for (int i = t; i < NBUCK; i += 256) lcount[i] = 0;
    __syncthreads();
    int base = blockIdx.x * EPB;
    unsigned rec[8]; int bp[8];
#pragma unroll
    for (int k = 0; k < 8; ++k) {
        int e = base + k * 256 + t;
        if (e < N_EDGES) {
            int r = row[e], c = col[e];
            int b = r >> 9;
            int pos = atomicAdd(&lcount[b], 1);        // rank within (block,bucket)
            atomicAdd(&deg[r], 1);                     // degree for h0's dinv
            rec[k] = ((unsigned)(r & 511) << 17) | (unsigned)c;
            bp[k] = (b << 16) | pos;
        } else bp[k] = -1;
    }
    __syncthreads();
    // reserve global space + exclusive scan of block-local counts
    int v = (t < NBUCK) ? lcount[t] : 0;
    if (t < NBUCK) lbase[t] = (v > 0) ? atomicAdd(&gcursor[t], v) : 0;
    sc[t] = v; __syncthreads();
    for (int off = 1; off < 256; off <<= 1) {
        int u = (t >= off) ? sc[t - off] : 0;
        __syncthreads();
        sc[t] += u;
        __syncthreads();
    }
    int excl = sc[t] - v;
    if (t < NBUCK) {
        sexcl[t] = excl;
        lbase[t] = t * BUCKCAP + lbase[t] - excl;      // folded: dest = lbase[b] + slot
    }
    __syncthreads();
    // bucket-sort records into LDS staging
#pragma unroll
    for (int k = 0; k < 8; ++k) {
        if (bp[k] >= 0) {
            int b = bp[k] >> 16, pos = bp[k] & 0xffff;
            int slot = sexcl[b] + pos;
            staged[slot] = rec[k];
            sdelta[slot] = lbase[b];
        }
    }
    __syncthreads();
    // coalesced copy-out: consecutive slots -> consecutive slab addrs per run
    int total = sc[255];
    for (int i = t; i < total; i += 256)
        slab[sdelta[i] + i] = staged[i];
}

// ------ S2 fused: blocks [0,NBUCK) build CSR; blocks [NBUCK,..) compute h0 --
// Independent halves: build consumes slab/gcursor; h0 consumes x/W/deg.
__global__ __launch_bounds__(256) void k_build_h0(const unsigned* __restrict__ slab,
        const int* __restrict__ gcursor,
        int* __restrict__ start, int* __restrict__ counts, float* __restrict__ dinv,
        unsigned* __restrict__ csr4,
        const float* __restrict__ x, const float* __restrict__ W,
        const float* __restrict__ bias, const int* __restrict__ deg,
        ushort_t* __restrict__ h0b, unsigned char* __restrict__ h0s) {
    __shared__ int ncount[BUCKN];
    __shared__ int nstart[BUCKN];
    __shared__ int sc[256];
    int b = blockIdx.x, t = threadIdx.x;
    if (b < NBUCK) {
        // ---------------- per-bucket CSR build, pad-to-4 --------------------
        int cnt = gcursor[b];
        int ebase = b * WINCAP;
        int node0 = b * BUCKN;
        int nn = min(BUCKN, N_NODES - node0);
        for (int i = t; i < nn; i += 256) ncount[i] = 0;
        __syncthreads();
        const unsigned* sl = slab + (size_t)b * BUCKCAP;
        for (int i = t; i < cnt; i += 256)
            atomicAdd(&ncount[sl[i] >> 17], 1);
        __syncthreads();
        int c0 = (2 * t < nn) ? ncount[2 * t] : 0;
        int c1 = (2 * t + 1 < nn) ? ncount[2 * t + 1] : 0;
        int p0 = (c0 + 3) & ~3, p1 = (c1 + 3) & ~3;
        int ps = p0 + p1;
        sc[t] = ps; __syncthreads();
        for (int off = 1; off < 256; off <<= 1) {
            int v = (t >= off) ? sc[t - off] : 0;
            __syncthreads();
            sc[t] += v;
            __syncthreads();
        }
        int ex = sc[t] - ps;
        if (2 * t < nn) nstart[2 * t] = ex;
        if (2 * t + 1 < nn) nstart[2 * t + 1] = ex + p0;
        __syncthreads();
        for (int i = t; i < nn; i += 256) {
            int node = node0 + i;
            int c = ncount[i];
            int pc = (c + 3) & ~3;
            int st = ebase + nstart[i];
            start[node] = st;
            counts[node] = pc;                        // PADDED count for the hop
            dinv[node] = rsqrtf((float)(c + 1));      // true degree for normalization
            for (int k = c; k < pc; ++k) csr4[st + k] = DUMMY;
        }
        __syncthreads();
        for (int i = t; i < cnt; i += 256) {
            unsigned r = sl[i];
            int pos = atomicAdd(&nstart[r >> 17], 1);
            csr4[ebase + pos] = r & 0x1ffffu;
        }
    } else {
        // ---------------- h0 = x @ W_sgc + b_sgc (bf16 + fp8) ---------------
        int wid = ((b - NBUCK) * 256 + t) >> 6;
        if (wid >= N_NODES / 16) return;
        int lane = t & 63;
        int row0 = wid * 16;
        int m = lane & 15, q = lane >> 4;

        frag_ab bfr[2][4];
#pragma unroll
        for (int ks = 0; ks < 2; ++ks)
#pragma unroll
            for (int nt = 0; nt < 4; ++nt)
#pragma unroll
                for (int j = 0; j < 8; ++j)
                    bfr[ks][nt][j] = (short)f2bf(W[(ks * 32 + q * 8 + j) * 64 + nt * 16 + m]);

        frag_ab afr[2];
#pragma unroll
        for (int ks = 0; ks < 2; ++ks) {
            const float4* xp = (const float4*)(x + (size_t)(row0 + m) * 64 + ks * 32 + q * 8);
            float4 v0 = xp[0], v1 = xp[1];
            afr[ks][0] = (short)f2bf(v0.x); afr[ks][1] = (short)f2bf(v0.y);
            afr[ks][2] = (short)f2bf(v0.z); afr[ks][3] = (short)f2bf(v0.w);
            afr[ks][4] = (short)f2bf(v1.x); afr[ks][5] = (short)f2bf(v1.y);
            afr[ks][6] = (short)f2bf(v1.z); afr[ks][7] = (short)f2bf(v1.w);
        }

        frag_cd acc[4];
#pragma unroll
        for (int nt = 0; nt < 4; ++nt) acc[nt] = (frag_cd){0.f, 0.f, 0.f, 0.f};
#pragma unroll
        for (int ks = 0; ks < 2; ++ks)
#pragma unroll
            for (int nt = 0; nt < 4; ++nt)
                acc[nt] = __builtin_amdgcn_mfma_f32_16x16x32_bf16(afr[ks], bfr[ks][nt], acc[nt], 0, 0, 0);

        float dv[4];
#pragma unroll
        for (int r = 0; r < 4; ++r)
            dv[r] = rsqrtf((float)(deg[row0 + q * 4 + r] + 1));   // same value bucket half writes

#pragma unroll
        for (int nt = 0; nt < 4; ++nt) {
            int cc = nt * 16 + m;
            float bl = bias[cc];
#pragma unroll
            for (int r = 0; r < 4; ++r) {
                int rr = row0 + q * 4 + r;
                float hv = acc[nt][r] + bl;
                h0b[(size_t)rr * 64 + cc] = f2bf(hv);
                h0s[(size_t)rr * 64 + cc] = f32_fp8(hv * dv[r]);   // byte store
            }
        }
        if (wid == 0) h0s[(size_t)N_NODES * 64 + lane] = 0;   // dummy row = 0
    }
}

// ---- hop inner sum: 16 lanes/node (4 nodes/wave), dword fp8 gathers --------
// lane l (0..15) handles features 4l..4l+3 (one dword = 4 fp8).
// Software-pipelined: next CSR uint4 issued before current group's gathers.
__device__ __forceinline__ void hop_sum4(int node, int l,
        const unsigned* __restrict__ hs_in, const int* __restrict__ start,
        const int* __restrict__ counts, const unsigned* __restrict__ csr4,
        float& a0, float& a1, float& a2, float& a3) {
    unsigned su = hs_in[node * 16 + l];            // self-loop term (hs form)
    floatx2 slo = fp8x2_lo(su), shi = fp8x2_hi(su);
    a0 = slo.x; a1 = slo.y; a2 = shi.x; a3 = shi.y;
    int st = start[node], cnt = counts[node];      // cnt % 4 == 0, st 16B-aligned
    if (cnt <= 0) return;
    uint4 cc = *(const uint4*)(csr4 + st);         // prologue group
    for (int j = 4; ; j += 4) {
        bool more = j < cnt;
        uint4 nx;
        if (more) nx = *(const uint4*)(csr4 + st + j);   // prefetch next group
        unsigned w0 = hs_in[cc.x * 16 + l];
        unsigned w1 = hs_in[cc.y * 16 + l];
        unsigned w2 = hs_in[cc.z * 16 + l];
        unsigned w3 = hs_in[cc.w * 16 + l];
        floatx2 l0 = fp8x2_lo(w0), h0 = fp8x2_hi(w0);
        floatx2 l1 = fp8x2_lo(w1), h1 = fp8x2_hi(w1);
        floatx2 l2 = fp8x2_lo(w2), h2 = fp8x2_hi(w2);
        floatx2 l3 = fp8x2_lo(w3), h3 = fp8x2_hi(w3);
        a0 += (l0.x + l1.x) + (l2.x + l3.x);
        a1 += (l0.y + l1.y) + (l2.y + l3.y);
        a2 += (h0.x + h1.x) + (h2.x + h3.x);
        a3 += (h0.y + h1.y) + (h2.y + h3.y);
        if (!more) break;
        cc = nx;
    }
}

// intermediate hop: residual from hs0 (fp8), writes fp8 hs_out (dword/lane):
//   hs_{k+1} = dinv * h_{k+1} = 0.5*di^2*S + 0.5*hs0
__global__ void k_hop(const unsigned* __restrict__ hs_in, const unsigned* __restrict__ hs0,
                      const float* __restrict__ dinv, const int* __restrict__ start,
                      const int* __restrict__ counts, const unsigned* __restrict__ csr4,
                      unsigned* __restrict__ hs_out) {
    int node = blockIdx.x * 16 + ((int)threadIdx.x >> 4);   // N_NODES % 16 == 0
    int l = threadIdx.x & 15;
    float a0, a1, a2, a3;
    hop_sum4(node, l, hs_in, start, counts, csr4, a0, a1, a2, a3);
    float di = dinv[node];
    float c = 0.5f * di * di;
    unsigned ru = hs0[node * 16 + l];
    floatx2 rlo = fp8x2_lo(ru), rhi = fp8x2_hi(ru);
    ushort_t lo = f32_fp8x2(c * a0 + 0.5f * rlo.x, c * a1 + 0.5f * rlo.y);
    ushort_t hi = f32_fp8x2(c * a2 + 0.5f * rhi.x, c * a3 + 0.5f * rhi.y);
    hs_out[node * 16 + l] = (unsigned)lo | ((unsigned)hi << 16);
    if (blockIdx.x == 0 && threadIdx.x < 16)
        hs_out[N_NODES * 16 + threadIdx.x] = 0;             // dummy row = 0
}

// final hop: bf16 h out (relu, residual from bf16 h0b) + attention gate
__global__ void k_hop_final(const unsigned* __restrict__ hs_in, const uint2* __restrict__ h0b2,
                            const float* __restrict__ dinv, const int* __restrict__ start,
                            const int* __restrict__ counts, const unsigned* __restrict__ csr4,
                            const float* __restrict__ w_att, const float* __restrict__ b_att,
                            uint2* __restrict__ h_out2, float* __restrict__ v_raw) {
    int node = blockIdx.x * 16 + ((int)threadIdx.x >> 4);
    int l = threadIdx.x & 15;
    float a0, a1, a2, a3;
    hop_sum4(node, l, hs_in, start, counts, csr4, a0, a1, a2, a3);
    float cdi = 0.5f * dinv[node];
    uint2 u = h0b2[node * 16 + l];
    float h0v = fmaxf(cdi * a0 + 0.5f * bf_lo(u.x), 0.f);
    float h1v = fmaxf(cdi * a1 + 0.5f * bf_hi(u.x), 0.f);
    float h2v = fmaxf(cdi * a2 + 0.5f * bf_lo(u.y), 0.f);
    float h3v = fmaxf(cdi * a3 + 0.5f * bf_hi(u.y), 0.f);
    uint2 o; o.x = pack2(h1v, h0v); o.y = pack2(h3v, h2v);
    h_out2[node * 16 + l] = o;
    float4 wa = *(const float4*)(w_att + 4 * l);
    float pp = (h0v * wa.x + h1v * wa.y) + (h2v * wa.z + h3v * wa.w);
#pragma unroll
    for (int off = 8; off >= 1; off >>= 1) pp += __shfl_xor(pp, off, 64);
    if (l == 0) {
        v_raw[node] = 1.f / (1.f + expf(-(pp + b_att[0])));
    }
}

// ---------------- readout + MLP head, one block per graph ----------------
__global__ void k_readout_mlp(const ushort_t* __restrict__ hb, const float* __restrict__ v_raw,
        const int* __restrict__ gbound,
        const float* __restrict__ W1, const float* __restrict__ b1,
        const float* __restrict__ W2, const float* __restrict__ b2,
        const float* __restrict__ W3, const float* __restrict__ b3,
        float* __restrict__ out) {
    int g = blockIdx.x, t = threadIdx.x;
    int s = gbound[g], e = gbound[g + 1];
    __shared__ float red[256];

    float m = -3.402823466e38f;
    for (int n = s + t; n < e; n += 256) m = fmaxf(m, v_raw[n]);
    red[t] = m; __syncthreads();
    for (int off = 128; off >= 1; off >>= 1) {
        if (t < off) red[t] = fmaxf(red[t], red[t + off]);
        __syncthreads();
    }
    float vmax = red[0]; __syncthreads();

    float ss = 0.f;
    for (int n = s + t; n < e; n += 256) ss += expf(v_raw[n] - vmax);
    red[t] = ss; __syncthreads();
    for (int off = 128; off >= 1; off >>= 1) {
        if (t < off) red[t] += red[t + off];
        __syncthreads();
    }
    float inv = 1.f / (red[0] + 1e-16f);
    __syncthreads();

    int wv = t >> 6, lane = t & 63;
    float gm = -3.402823466e38f, gs = 0.f;
    for (int n = s + wv; n < e; n += 4) {
        float hv = bf2f(hb[(size_t)n * 64 + lane]);
        float vn = expf(v_raw[n] - vmax) * inv;
        gm = fmaxf(gm, hv);
        gs += vn * hv;
    }
    __shared__ float pm[4][64], ps[4][64];
    pm[wv][lane] = gm; ps[wv][lane] = gs;
    __syncthreads();

    __shared__ float z[128];
    if (t < 64) {
        z[t] = fmaxf(fmaxf(pm[0][t], pm[1][t]), fmaxf(pm[2][t], pm[3][t]));
        z[64 + t] = ps[0][t] + ps[1][t] + ps[2][t] + ps[3][t];
    }
    __syncthreads();

    __shared__ float z1[64];
    if (t < 64) {
        float a = b1[t];
#pragma unroll 8
        for (int k = 0; k < 128; ++k) a += z[k] * W1[k * 64 + t];
        z1[t] = fmaxf(a, 0.f);
    }
    __syncthreads();
    __shared__ float z2[32];
    if (t < 32) {
        float a = b2[t];
#pragma unroll 8
        for (int k = 0; k < 64; ++k) a += z1[k] * W2[k * 32 + t];
        z2[t] = fmaxf(a, 0.f);
    }
    __syncthreads();
    __shared__ float z3[8];
    if (t < 8) {
        float a = b3[t];
#pragma unroll
        for (int k = 0; k < 32; ++k) a += z2[k] * W3[k * 8 + t];
        z3[t] = a;
    }
    __syncthreads();
    if (t == 0) {
        float mx = z3[0];
#pragma unroll
        for (int j = 1; j < 8; ++j) mx = fmaxf(mx, z3[j]);
        float se = 0.f;
#pragma unroll
        for (int j = 0; j < 8; ++j) se += expf(z3[j] - mx);
        float lse = mx + logf(se);
#pragma unroll
        for (int j = 0; j < 8; ++j) out[g * 8 + j] = z3[j] - lse;
    }
}

extern "C" void kernel_launch(void* const* d_in, const int* in_sizes, int n_in,
                              void* d_out, int out_size, void* d_ws, size_t ws_size,
                              hipStream_t stream) {
    const float* x     = (const float*)d_in[0];
    const int*   edge  = (const int*)d_in[1];
    const int*   row   = edge;
    const int*   col   = edge + N_EDGES;
    const int*   batch = (const int*)d_in[2];
    const float* W_sgc = (const float*)d_in[3];
    const float* b_sgc = (const float*)d_in[4];
    const float* w_att = (const float*)d_in[5];
    const float* b_att = (const float*)d_in[6];
    const float* W1    = (const float*)d_in[7];
    const float* b1    = (const float*)d_in[8];
    const float* W2    = (const float*)d_in[9];
    const float* b2    = (const float*)d_in[10];
    const float* W3    = (const float*)d_in[11];
    const float* b3    = (const float*)d_in[12];
    float* out = (float*)d_out;

    char* p = (char*)d_ws;
    auto alloc = [&](size_t bytes) {
        char* r = p;
        p += (bytes + 255) & ~(size_t)255;
        return r;
    };
    int*      gcursor = (int*)alloc((size_t)NBUCK * 4);          // zeroed below
    int*      deg     = (int*)alloc((size_t)N_NODES * 4);        // zeroed below (adjacent)
    int*      gbound  = (int*)alloc((size_t)(NGRAPH + 1) * 4);
    int*      start   = (int*)alloc((size_t)N_NODES * 4);
    int*      counts  = (int*)alloc((size_t)N_NODES * 4);
    float*    dinv    = (float*)alloc((size_t)N_NODES * 4);
    float*    vraw    = (float*)alloc((size_t)N_NODES * 4);
    ushort_t* h0b     = (ushort_t*)alloc((size_t)N_NODES * 64 * 2);          // bf16
    unsigned char* h0s = (unsigned char*)alloc((size_t)(N_NODES + 1) * 64);  // fp8
    ushort_t* hAs     = (ushort_t*)alloc((size_t)(N_NODES + 1) * 32 * 2);    // fp8
    ushort_t* hBs     = (ushort_t*)alloc((size_t)(N_NODES + 1) * 32 * 2);    // fp8
    ushort_t* hfin    = (ushort_t*)alloc((size_t)N_NODES * 64 * 2);          // bf16 final h
    unsigned* csr4    = (unsigned*)alloc(((size_t)NBUCK * WINCAP + 64) * 4); // fixed windows
    unsigned* slab    = (unsigned*)alloc((size_t)NBUCK * BUCKCAP * 4);

    // one memset spans gcursor (padded to 1024B) + deg (adjacent allocation)
    hipMemsetAsync(gcursor, 0, (size_t)1024 + (size_t)N_NODES * 4, stream);

    k_binstage_bounds<<<NBIN_BLOCKS + NBOUND_BLOCKS, 256, 0, stream>>>(
        row, col, gcursor, slab, batch, gbound, deg);
    k_build_h0<<<NBUCK + H0_BLOCKS, 256, 0, stream>>>(
        slab, gcursor, start, counts, dinv, csr4,
        x, W_sgc, b_sgc, deg, h0b, (unsigned char*)h0s);
    k_hop<<<N_NODES / 16, 256, 0, stream>>>((const unsigned*)h0s, (const unsigned*)h0s,
                                            dinv, start, counts, csr4, (unsigned*)hAs);
    k_hop<<<N_NODES / 16, 256, 0, stream>>>((const unsigned*)hAs, (const unsigned*)h0s,
                                            dinv, start, counts, csr4, (unsigned*)hBs);
    k_hop_final<<<N_NODES / 16, 256, 0, stream>>>((const unsigned*)hBs, (const uint2*)h0b,
                                                  dinv, start, counts, csr4,
                                                  w_att, b_att, (uint2*)hfin, vraw);
    k_readout_mlp<<<NGRAPH, 256, 0, stream>>>(hfin, vraw, gbound,
                                              W1, b1, W2, b2, W3, b3, out);
}

// Round 9
// 228.986 us; speedup vs baseline: 1.3522x; 1.1246x over previous
//
#include <hip/hip_runtime.h>
#include <math.h>

#define N_NODES 100000
#define N_EDGES 1000000
#define NGRAPH 256

#define NBUCK 196          // ceil(100000 / 512)
#define BUCKN 512
#define BUCKCAP 8192       // max raw edges/bucket (mean ~5120, ~40 sigma margin)
#define EPB 2048           // edges per bin block (8/thread)
#define NBIN_BLOCKS ((N_EDGES + EPB - 1) / EPB)          // 489
#define NBOUND_BLOCKS ((N_NODES + 255) / 256)            // 391
#define WINCAP 10240       // fixed csr window per bucket
#define DUMMY ((unsigned)N_NODES)   // pad col -> node with hs == 0
#define H0_BLOCKS ((N_NODES / 16 + 3) / 4)               // 1563

typedef unsigned short ushort_t;
typedef __attribute__((ext_vector_type(2))) float floatx2;

__device__ __forceinline__ ushort_t f2bf(float f) {   // round-to-nearest-even
    unsigned u = __float_as_uint(f);
    u += 0x7fffu + ((u >> 16) & 1u);
    return (ushort_t)(u >> 16);
}
__device__ __forceinline__ float bf2f(ushort_t u) {
    return __uint_as_float(((unsigned)u) << 16);
}
__device__ __forceinline__ float bf_lo(unsigned u) {
    return __uint_as_float(u << 16);
}
__device__ __forceinline__ float bf_hi(unsigned u) {
    return __uint_as_float(u & 0xffff0000u);
}
__device__ __forceinline__ unsigned pack2(float hi, float lo) {
    return ((unsigned)f2bf(hi) << 16) | (unsigned)f2bf(lo);
}
// fp8 e4m3 (OCP) HW converts, gfx950
__device__ __forceinline__ floatx2 fp8x2_lo(unsigned u) {       // bytes 0,1
    return __builtin_amdgcn_cvt_pk_f32_fp8(u, false);
}
__device__ __forceinline__ floatx2 fp8x2_hi(unsigned u) {       // bytes 2,3
    return __builtin_amdgcn_cvt_pk_f32_fp8(u, true);
}
__device__ __forceinline__ ushort_t f32_fp8x2(float a, float b) {
    return (ushort_t)(__builtin_amdgcn_cvt_pk_fp8_f32(a, b, 0u, false) & 0xffffu);
}

using frag_ab = __attribute__((ext_vector_type(8))) short;
using frag_cd = __attribute__((ext_vector_type(4))) float;

// ---- K1: blocks [0,489) bin (coalesced staging, NO global atoms on deg);
//          [489,880) graph bounds; [880,2443) h0 = x@W+b in bf16 (h0b only) --
__global__ __launch_bounds__(256) void k_bin_bounds_h0(const int* __restrict__ row,
        const int* __restrict__ col, int* __restrict__ gcursor,
        unsigned* __restrict__ slab,
        const int* __restrict__ batch, int* __restrict__ gbound,
        const float* __restrict__ x, const float* __restrict__ W,
        const float* __restrict__ bias, ushort_t* __restrict__ h0b) {
    __shared__ int lcount[NBUCK];
    __shared__ int lbase[NBUCK];       // reserve, then folded dest base
    __shared__ int sexcl[NBUCK];       // block-local exclusive scan
    __shared__ int sc[256];
    __shared__ unsigned staged[EPB];
    __shared__ int sdelta[EPB];
    int t = threadIdx.x;
    int b = blockIdx.x;
    if (b >= NBIN_BLOCKS + NBOUND_BLOCKS) {
        // ---------------- h0 = x @ W_sgc + b_sgc (bf16 only) ----------------
        int wid = ((b - NBIN_BLOCKS - NBOUND_BLOCKS) * 256 + t) >> 6;
        if (wid >= N_NODES / 16) return;
        int lane = t & 63;
        int row0 = wid * 16;
        int m = lane & 15, q = lane >> 4;

        frag_ab bfr[2][4];
#pragma unroll
        for (int ks = 0; ks < 2; ++ks)
#pragma unroll
            for (int nt = 0; nt < 4; ++nt)
#pragma unroll
                for (int j = 0; j < 8; ++j)
                    bfr[ks][nt][j] = (short)f2bf(W[(ks * 32 + q * 8 + j) * 64 + nt * 16 + m]);

        frag_ab afr[2];
#pragma unroll
        for (int ks = 0; ks < 2; ++ks) {
            const float4* xp = (const float4*)(x + (size_t)(row0 + m) * 64 + ks * 32 + q * 8);
            float4 v0 = xp[0], v1 = xp[1];
            afr[ks][0] = (short)f2bf(v0.x); afr[ks][1] = (short)f2bf(v0.y);
            afr[ks][2] = (short)f2bf(v0.z); afr[ks][3] = (short)f2bf(v0.w);
            afr[ks][4] = (short)f2bf(v1.x); afr[ks][5] = (short)f2bf(v1.y);
            afr[ks][6] = (short)f2bf(v1.z); afr[ks][7] = (short)f2bf(v1.w);
        }

        frag_cd acc[4];
#pragma unroll
        for (int nt = 0; nt < 4; ++nt) acc[nt] = (frag_cd){0.f, 0.f, 0.f, 0.f};
#pragma unroll
        for (int ks = 0; ks < 2; ++ks)
#pragma unroll
            for (int nt = 0; nt < 4; ++nt)
                acc[nt] = __builtin_amdgcn_mfma_f32_16x16x32_bf16(afr[ks], bfr[ks][nt], acc[nt], 0, 0, 0);

#pragma unroll
        for (int nt = 0; nt < 4; ++nt) {
            int cc = nt * 16 + m;
            float bl = bias[cc];
#pragma unroll
            for (int r = 0; r < 4; ++r) {
                int rr = row0 + q * 4 + r;
                h0b[(size_t)rr * 64 + cc] = f2bf(acc[nt][r] + bl);
            }
        }
        return;
    }
    if (b >= NBIN_BLOCKS) {
        int n = (b - NBIN_BLOCKS) * 256 + t;
        if (n >= N_NODES) return;
        int bb = batch[n];
        int prev = (n == 0) ? -1 : batch[n - 1];
        for (int g = prev + 1; g <= bb; ++g) gbound[g] = n;
        if (n == N_NODES - 1) {
            for (int g = bb + 1; g <= NGRAPH; ++g) gbound[g] = N_NODES;
        }
        return;
    }
    // ---------------- coalesced LDS-staged binning --------------------------
    for (int i = t; i < NBUCK; i += 256) lcount[i] = 0;
    __syncthreads();
    int base = b * EPB;
    unsigned rec[8]; int bp[8];
#pragma unroll
    for (int k = 0; k < 8; ++k) {
        int e = base + k * 256 + t;
        if (e < N_EDGES) {
            int r = row[e], c = col[e];
            int bk = r >> 9;
            int pos = atomicAdd(&lcount[bk], 1);       // rank within (block,bucket)
            rec[k] = ((unsigned)(r & 511) << 17) | (unsigned)c;
            bp[k] = (bk << 16) | pos;
        } else bp[k] = -1;
    }
    __syncthreads();
    // reserve global space + exclusive scan of block-local counts
    int v = (t < NBUCK) ? lcount[t] : 0;
    if (t < NBUCK) lbase[t] = (v > 0) ? atomicAdd(&gcursor[t], v) : 0;
    sc[t] = v; __syncthreads();
    for (int off = 1; off < 256; off <<= 1) {
        int u = (t >= off) ? sc[t - off] : 0;
        __syncthreads();
        sc[t] += u;
        __syncthreads();
    }
    int excl = sc[t] - v;
    if (t < NBUCK) {
        sexcl[t] = excl;
        lbase[t] = t * BUCKCAP + lbase[t] - excl;      // folded: dest = lbase[b] + slot
    }
    __syncthreads();
    // bucket-sort records into LDS staging
#pragma unroll
    for (int k = 0; k < 8; ++k) {
        if (bp[k] >= 0) {
            int bk = bp[k] >> 16, pos = bp[k] & 0xffff;
            int slot = sexcl[bk] + pos;
            staged[slot] = rec[k];
            sdelta[slot] = lbase[bk];
        }
    }
    __syncthreads();
    // coalesced copy-out: consecutive slots -> consecutive slab addrs per run
    int total = sc[255];
    for (int i = t; i < total; i += 256)
        slab[sdelta[i] + i] = staged[i];
}

// ---- K2: per-bucket CSR build + fused h0s = fp8(h0b * dinv) scale ----------
__global__ __launch_bounds__(256) void k_build_scale(const unsigned* __restrict__ slab,
        const int* __restrict__ gcursor,
        int* __restrict__ start, int* __restrict__ counts, float* __restrict__ dinv,
        unsigned* __restrict__ csr4,
        const ushort_t* __restrict__ h0b, unsigned char* __restrict__ h0s) {
    __shared__ int ncount[BUCKN];
    __shared__ int nstart[BUCKN];
    __shared__ int sc[256];
    __shared__ float sdv[BUCKN];
    int b = blockIdx.x, t = threadIdx.x;
    int cnt = gcursor[b];
    int ebase = b * WINCAP;
    int node0 = b * BUCKN;
    int nn = min(BUCKN, N_NODES - node0);
    for (int i = t; i < nn; i += 256) ncount[i] = 0;
    __syncthreads();
    const unsigned* sl = slab + (size_t)b * BUCKCAP;
    for (int i = t; i < cnt; i += 256)
        atomicAdd(&ncount[sl[i] >> 17], 1);
    __syncthreads();
    int c0 = (2 * t < nn) ? ncount[2 * t] : 0;
    int c1 = (2 * t + 1 < nn) ? ncount[2 * t + 1] : 0;
    int p0 = (c0 + 3) & ~3, p1 = (c1 + 3) & ~3;
    int ps = p0 + p1;
    sc[t] = ps; __syncthreads();
    for (int off = 1; off < 256; off <<= 1) {
        int v = (t >= off) ? sc[t - off] : 0;
        __syncthreads();
        sc[t] += v;
        __syncthreads();
    }
    int ex = sc[t] - ps;
    if (2 * t < nn) nstart[2 * t] = ex;
    if (2 * t + 1 < nn) nstart[2 * t + 1] = ex + p0;
    __syncthreads();
    for (int i = t; i < nn; i += 256) {
        int node = node0 + i;
        int c = ncount[i];
        int pc = (c + 3) & ~3;
        int st = ebase + nstart[i];
        start[node] = st;
        counts[node] = pc;                        // PADDED count for the hop
        float dv = rsqrtf((float)(c + 1));        // true degree for normalization
        dinv[node] = dv;
        sdv[i] = dv;
        for (int k = c; k < pc; ++k) csr4[st + k] = DUMMY;
    }
    __syncthreads();
    for (int i = t; i < cnt; i += 256) {
        unsigned r = sl[i];
        int pos = atomicAdd(&nstart[r >> 17], 1);
        csr4[ebase + pos] = r & 0x1ffffu;
    }
    // ---- fused scale: h0s[node][:] = fp8(h0b[node][:] * dinv[node]) --------
    const uint4* hp = (const uint4*)h0b;          // 16B = 8 bf16 per chunk
    uint2* op = (uint2*)h0s;                      // 8B  = 8 fp8 per chunk
    int nch = nn * 8;                             // 8 chunks per 64-feat row
    for (int i = t; i < nch; i += 256) {
        float dv = sdv[i >> 3];
        uint4 vch = hp[(size_t)node0 * 8 + i];
        ushort_t s0 = f32_fp8x2(bf_lo(vch.x) * dv, bf_hi(vch.x) * dv);
        ushort_t s1 = f32_fp8x2(bf_lo(vch.y) * dv, bf_hi(vch.y) * dv);
        ushort_t s2 = f32_fp8x2(bf_lo(vch.z) * dv, bf_hi(vch.z) * dv);
        ushort_t s3 = f32_fp8x2(bf_lo(vch.w) * dv, bf_hi(vch.w) * dv);
        uint2 o;
        o.x = (unsigned)s0 | ((unsigned)s1 << 16);
        o.y = (unsigned)s2 | ((unsigned)s3 << 16);
        op[(size_t)node0 * 8 + i] = o;
    }
    if (b == 0 && t < 16) ((unsigned*)(h0s + (size_t)N_NODES * 64))[t] = 0;  // dummy row
}

// ---- hop inner sum: 16 lanes/node (4 nodes/wave), dword fp8 gathers --------
// lane l (0..15) handles features 4l..4l+3 (one dword = 4 fp8).
// Software-pipelined: next CSR uint4 issued before current group's gathers.
__device__ __forceinline__ void hop_sum4(int node, int l,
        const unsigned* __restrict__ hs_in, const int* __restrict__ start,
        const int* __restrict__ counts, const unsigned* __restrict__ csr4,
        float& a0, float& a1, float& a2, float& a3) {
    unsigned su = hs_in[node * 16 + l];            // self-loop term (hs form)
    floatx2 slo = fp8x2_lo(su), shi = fp8x2_hi(su);
    a0 = slo.x; a1 = slo.y; a2 = shi.x; a3 = shi.y;
    int st = start[node], cnt = counts[node];      // cnt % 4 == 0, st 16B-aligned
    if (cnt <= 0) return;
    uint4 cc = *(const uint4*)(csr4 + st);         // prologue group
    for (int j = 4; ; j += 4) {
        bool more = j < cnt;
        uint4 nx;
        if (more) nx = *(const uint4*)(csr4 + st + j);   // prefetch next group
        unsigned w0 = hs_in[cc.x * 16 + l];
        unsigned w1 = hs_in[cc.y * 16 + l];
        unsigned w2 = hs_in[cc.z * 16 + l];
        unsigned w3 = hs_in[cc.w * 16 + l];
        floatx2 l0 = fp8x2_lo(w0), h0 = fp8x2_hi(w0);
        floatx2 l1 = fp8x2_lo(w1), h1 = fp8x2_hi(w1);
        floatx2 l2 = fp8x2_lo(w2), h2 = fp8x2_hi(w2);
        floatx2 l3 = fp8x2_lo(w3), h3 = fp8x2_hi(w3);
        a0 += (l0.x + l1.x) + (l2.x + l3.x);
        a1 += (l0.y + l1.y) + (l2.y + l3.y);
        a2 += (h0.x + h1.x) + (h2.x + h3.x);
        a3 += (h0.y + h1.y) + (h2.y + h3.y);
        if (!more) break;
        cc = nx;
    }
}

// intermediate hop: residual from hs0 (fp8), writes fp8 hs_out (dword/lane):
//   hs_{k+1} = dinv * h_{k+1} = 0.5*di^2*S + 0.5*hs0
__global__ void k_hop(const unsigned* __restrict__ hs_in, const unsigned* __restrict__ hs0,
                      const float* __restrict__ dinv, const int* __restrict__ start,
                      const int* __restrict__ counts, const unsigned* __restrict__ csr4,
                      unsigned* __restrict__ hs_out) {
    int node = blockIdx.x * 16 + ((int)threadIdx.x >> 4);   // N_NODES % 16 == 0
    int l = threadIdx.x & 15;
    float a0, a1, a2, a3;
    hop_sum4(node, l, hs_in, start, counts, csr4, a0, a1, a2, a3);
    float di = dinv[node];
    float c = 0.5f * di * di;
    unsigned ru = hs0[node * 16 + l];
    floatx2 rlo = fp8x2_lo(ru), rhi = fp8x2_hi(ru);
    ushort_t lo = f32_fp8x2(c * a0 + 0.5f * rlo.x, c * a1 + 0.5f * rlo.y);
    ushort_t hi = f32_fp8x2(c * a2 + 0.5f * rhi.x, c * a3 + 0.5f * rhi.y);
    hs_out[node * 16 + l] = (unsigned)lo | ((unsigned)hi << 16);
    if (blockIdx.x == 0 && threadIdx.x < 16)
        hs_out[N_NODES * 16 + threadIdx.x] = 0;             // dummy row = 0
}

// final hop: bf16 h out (relu, residual from bf16 h0b) + attention gate
__global__ void k_hop_final(const unsigned* __restrict__ hs_in, const uint2* __restrict__ h0b2,
                            const float* __restrict__ dinv, const int* __restrict__ start,
                            const int* __restrict__ counts, const unsigned* __restrict__ csr4,
                            const float* __restrict__ w_att, const float* __restrict__ b_att,
                            uint2* __restrict__ h_out2, float* __restrict__ v_raw) {
    int node = blockIdx.x * 16 + ((int)threadIdx.x >> 4);
    int l = threadIdx.x & 15;
    float a0, a1, a2, a3;
    hop_sum4(node, l, hs_in, start, counts, csr4, a0, a1, a2, a3);
    float cdi = 0.5f * dinv[node];
    uint2 u = h0b2[node * 16 + l];
    float h0v = fmaxf(cdi * a0 + 0.5f * bf_lo(u.x), 0.f);
    float h1v = fmaxf(cdi * a1 + 0.5f * bf_hi(u.x), 0.f);
    float h2v = fmaxf(cdi * a2 + 0.5f * bf_lo(u.y), 0.f);
    float h3v = fmaxf(cdi * a3 + 0.5f * bf_hi(u.y), 0.f);
    uint2 o; o.x = pack2(h1v, h0v); o.y = pack2(h3v, h2v);
    h_out2[node * 16 + l] = o;
    float4 wa = *(const float4*)(w_att + 4 * l);
    float pp = (h0v * wa.x + h1v * wa.y) + (h2v * wa.z + h3v * wa.w);
#pragma unroll
    for (int off = 8; off >= 1; off >>= 1) pp += __shfl_xor(pp, off, 64);
    if (l == 0) {
        v_raw[node] = 1.f / (1.f + expf(-(pp + b_att[0])));
    }
}

// ---------------- readout + MLP head, one block per graph ----------------
__global__ void k_readout_mlp(const ushort_t* __restrict__ hb, const float* __restrict__ v_raw,
        const int* __restrict__ gbound,
        const float* __restrict__ W1, const float* __restrict__ b1,
        const float* __restrict__ W2, const float* __restrict__ b2,
        const float* __restrict__ W3, const float* __restrict__ b3,
        float* __restrict__ out) {
    int g = blockIdx.x, t = threadIdx.x;
    int s = gbound[g], e = gbound[g + 1];
    __shared__ float red[256];

    float m = -3.402823466e38f;
    for (int n = s + t; n < e; n += 256) m = fmaxf(m, v_raw[n]);
    red[t] = m; __syncthreads();
    for (int off = 128; off >= 1; off >>= 1) {
        if (t < off) red[t] = fmaxf(red[t], red[t + off]);
        __syncthreads();
    }
    float vmax = red[0]; __syncthreads();

    float ss = 0.f;
    for (int n = s + t; n < e; n += 256) ss += expf(v_raw[n] - vmax);
    red[t] = ss; __syncthreads();
    for (int off = 128; off >= 1; off >>= 1) {
        if (t < off) red[t] += red[t + off];
        __syncthreads();
    }
    float inv = 1.f / (red[0] + 1e-16f);
    __syncthreads();

    int wv = t >> 6, lane = t & 63;
    float gm = -3.402823466e38f, gs = 0.f;
    for (int n = s + wv; n < e; n += 4) {
        float hv = bf2f(hb[(size_t)n * 64 + lane]);
        float vn = expf(v_raw[n] - vmax) * inv;
        gm = fmaxf(gm, hv);
        gs += vn * hv;
    }
    __shared__ float pm[4][64], ps[4][64];
    pm[wv][lane] = gm; ps[wv][lane] = gs;
    __syncthreads();

    __shared__ float z[128];
    if (t < 64) {
        z[t] = fmaxf(fmaxf(pm[0][t], pm[1][t]), fmaxf(pm[2][t], pm[3][t]));
        z[64 + t] = ps[0][t] + ps[1][t] + ps[2][t] + ps[3][t];
    }
    __syncthreads();

    __shared__ float z1[64];
    if (t < 64) {
        float a = b1[t];
#pragma unroll 8
        for (int k = 0; k < 128; ++k) a += z[k] * W1[k * 64 + t];
        z1[t] = fmaxf(a, 0.f);
    }
    __syncthreads();
    __shared__ float z2[32];
    if (t < 32) {
        float a = b2[t];
#pragma unroll 8
        for (int k = 0; k < 64; ++k) a += z1[k] * W2[k * 32 + t];
        z2[t] = fmaxf(a, 0.f);
    }
    __syncthreads();
    __shared__ float z3[8];
    if (t < 8) {
        float a = b3[t];
#pragma unroll
        for (int k = 0; k < 32; ++k) a += z2[k] * W3[k * 8 + t];
        z3[t] = a;
    }
    __syncthreads();
    if (t == 0) {
        float mx = z3[0];
#pragma unroll
        for (int j = 1; j < 8; ++j) mx = fmaxf(mx, z3[j]);
        float se = 0.f;
#pragma unroll
        for (int j = 0; j < 8; ++j) se += expf(z3[j] - mx);
        float lse = mx + logf(se);
#pragma unroll
        for (int j = 0; j < 8; ++j) out[g * 8 + j] = z3[j] - lse;
    }
}

extern "C" void kernel_launch(void* const* d_in, const int* in_sizes, int n_in,
                              void* d_out, int out_size, void* d_ws, size_t ws_size,
                              hipStream_t stream) {
    const float* x     = (const float*)d_in[0];
    const int*   edge  = (const int*)d_in[1];
    const int*   row   = edge;
    const int*   col   = edge + N_EDGES;
    const int*   batch = (const int*)d_in[2];
    const float* W_sgc = (const float*)d_in[3];
    const float* b_sgc = (const float*)d_in[4];
    const float* w_att = (const float*)d_in[5];
    const float* b_att = (const float*)d_in[6];
    const float* W1    = (const float*)d_in[7];
    const float* b1    = (const float*)d_in[8];
    const float* W2    = (const float*)d_in[9];
    const float* b2    = (const float*)d_in[10];
    const float* W3    = (const float*)d_in[11];
    const float* b3    = (const float*)d_in[12];
    float* out = (float*)d_out;

    char* p = (char*)d_ws;
    auto alloc = [&](size_t bytes) {
        char* r = p;
        p += (bytes + 255) & ~(size_t)255;
        return r;
    };
    int*      gcursor = (int*)alloc((size_t)NBUCK * 4);          // zeroed below
    int*      gbound  = (int*)alloc((size_t)(NGRAPH + 1) * 4);
    int*      start   = (int*)alloc((size_t)N_NODES * 4);
    int*      counts  = (int*)alloc((size_t)N_NODES * 4);
    float*    dinv    = (float*)alloc((size_t)N_NODES * 4);
    float*    vraw    = (float*)alloc((size_t)N_NODES * 4);
    ushort_t* h0b     = (ushort_t*)alloc((size_t)N_NODES * 64 * 2);          // bf16
    unsigned char* h0s = (unsigned char*)alloc((size_t)(N_NODES + 1) * 64);  // fp8
    ushort_t* hAs     = (ushort_t*)alloc((size_t)(N_NODES + 1) * 32 * 2);    // fp8
    ushort_t* hBs     = (ushort_t*)alloc((size_t)(N_NODES + 1) * 32 * 2);    // fp8
    ushort_t* hfin    = (ushort_t*)alloc((size_t)N_NODES * 64 * 2);          // bf16 final h
    unsigned* csr4    = (unsigned*)alloc(((size_t)NBUCK * WINCAP + 64) * 4); // fixed windows
    unsigned* slab    = (unsigned*)alloc((size_t)NBUCK * BUCKCAP * 4);

    hipMemsetAsync(gcursor, 0, (size_t)NBUCK * 4, stream);

    k_bin_bounds_h0<<<NBIN_BLOCKS + NBOUND_BLOCKS + H0_BLOCKS, 256, 0, stream>>>(
        row, col, gcursor, slab, batch, gbound, x, W_sgc, b_sgc, h0b);
    k_build_scale<<<NBUCK, 256, 0, stream>>>(slab, gcursor, start, counts, dinv, csr4,
                                             h0b, (unsigned char*)h0s);
    k_hop<<<N_NODES / 16, 256, 0, stream>>>((const unsigned*)h0s, (const unsigned*)h0s,
                                            dinv, start, counts, csr4, (unsigned*)hAs);
    k_hop<<<N_NODES / 16, 256, 0, stream>>>((const unsigned*)hAs, (const unsigned*)h0s,
                                            dinv, start, counts, csr4, (unsigned*)hBs);
    k_hop_final<<<N_NODES / 16, 256, 0, stream>>>((const unsigned*)hBs, (const uint2*)h0b,
                                                  dinv, start, counts, csr4,
                                                  w_att, b_att, (uint2*)hfin, vraw);
    k_readout_mlp<<<NGRAPH, 256, 0, stream>>>(hfin, vraw, gbound,
                                              W1, b1, W2, b2, W3, b3, out);
}

// Round 10
// 221.800 us; speedup vs baseline: 1.3960x; 1.0324x over previous
//
#include <hip/hip_runtime.h>
#include <math.h>

#define N_NODES 100000
#define N_EDGES 1000000
#define NGRAPH 256

#define NBUCK 196          // ceil(100000 / 512)
#define BUCKN 512
#define BUCKCAP 8192       // max raw edges/bucket (mean ~5120, ~40 sigma margin)
#define EPB 2048           // edges per bin block (8/thread)
#define NBIN_BLOCKS ((N_EDGES + EPB - 1) / EPB)          // 489
#define NBOUND_BLOCKS ((N_NODES + 255) / 256)            // 391
#define WINCAP 10240       // fixed csr window per bucket (pad16 mean ~8400, 3.5s ~8620)
#define DUMMY ((unsigned)N_NODES)   // pad col -> node with hs == 0
#define H0_BLOCKS ((N_NODES / 16 + 3) / 4)               // 1563

typedef unsigned short ushort_t;
typedef __attribute__((ext_vector_type(2))) float floatx2;

__device__ __forceinline__ ushort_t f2bf(float f) {   // round-to-nearest-even
    unsigned u = __float_as_uint(f);
    u += 0x7fffu + ((u >> 16) & 1u);
    return (ushort_t)(u >> 16);
}
__device__ __forceinline__ float bf2f(ushort_t u) {
    return __uint_as_float(((unsigned)u) << 16);
}
__device__ __forceinline__ float bf_lo(unsigned u) {
    return __uint_as_float(u << 16);
}
__device__ __forceinline__ float bf_hi(unsigned u) {
    return __uint_as_float(u & 0xffff0000u);
}
__device__ __forceinline__ unsigned pack2(float hi, float lo) {
    return ((unsigned)f2bf(hi) << 16) | (unsigned)f2bf(lo);
}
// fp8 e4m3 (OCP) HW converts, gfx950
__device__ __forceinline__ floatx2 fp8x2_lo(unsigned u) {       // bytes 0,1
    return __builtin_amdgcn_cvt_pk_f32_fp8(u, false);
}
__device__ __forceinline__ floatx2 fp8x2_hi(unsigned u) {       // bytes 2,3
    return __builtin_amdgcn_cvt_pk_f32_fp8(u, true);
}
__device__ __forceinline__ ushort_t f32_fp8x2(float a, float b) {
    return (ushort_t)(__builtin_amdgcn_cvt_pk_fp8_f32(a, b, 0u, false) & 0xffffu);
}

using frag_ab = __attribute__((ext_vector_type(8))) short;
using frag_cd = __attribute__((ext_vector_type(4))) float;

// ---- K1: blocks [0,489) bin (coalesced staging); [489,880) graph bounds;
//          [880,2443) h0 = x@W+b in bf16 (h0b only) ------------------------
__global__ __launch_bounds__(256) void k_bin_bounds_h0(const int* __restrict__ row,
        const int* __restrict__ col, int* __restrict__ gcursor,
        unsigned* __restrict__ slab,
        const int* __restrict__ batch, int* __restrict__ gbound,
        const float* __restrict__ x, const float* __restrict__ W,
        const float* __restrict__ bias, ushort_t* __restrict__ h0b) {
    __shared__ int lcount[NBUCK];
    __shared__ int lbase[NBUCK];       // reserve, then folded dest base
    __shared__ int sexcl[NBUCK];       // block-local exclusive scan
    __shared__ int sc[256];
    __shared__ unsigned staged[EPB];
    __shared__ int sdelta[EPB];
    int t = threadIdx.x;
    int b = blockIdx.x;
    if (b >= NBIN_BLOCKS + NBOUND_BLOCKS) {
        // ---------------- h0 = x @ W_sgc + b_sgc (bf16 only) ----------------
        int wid = ((b - NBIN_BLOCKS - NBOUND_BLOCKS) * 256 + t) >> 6;
        if (wid >= N_NODES / 16) return;
        int lane = t & 63;
        int row0 = wid * 16;
        int m = lane & 15, q = lane >> 4;

        frag_ab bfr[2][4];
#pragma unroll
        for (int ks = 0; ks < 2; ++ks)
#pragma unroll
            for (int nt = 0; nt < 4; ++nt)
#pragma unroll
                for (int j = 0; j < 8; ++j)
                    bfr[ks][nt][j] = (short)f2bf(W[(ks * 32 + q * 8 + j) * 64 + nt * 16 + m]);

        frag_ab afr[2];
#pragma unroll
        for (int ks = 0; ks < 2; ++ks) {
            const float4* xp = (const float4*)(x + (size_t)(row0 + m) * 64 + ks * 32 + q * 8);
            float4 v0 = xp[0], v1 = xp[1];
            afr[ks][0] = (short)f2bf(v0.x); afr[ks][1] = (short)f2bf(v0.y);
            afr[ks][2] = (short)f2bf(v0.z); afr[ks][3] = (short)f2bf(v0.w);
            afr[ks][4] = (short)f2bf(v1.x); afr[ks][5] = (short)f2bf(v1.y);
            afr[ks][6] = (short)f2bf(v1.z); afr[ks][7] = (short)f2bf(v1.w);
        }

        frag_cd acc[4];
#pragma unroll
        for (int nt = 0; nt < 4; ++nt) acc[nt] = (frag_cd){0.f, 0.f, 0.f, 0.f};
#pragma unroll
        for (int ks = 0; ks < 2; ++ks)
#pragma unroll
            for (int nt = 0; nt < 4; ++nt)
                acc[nt] = __builtin_amdgcn_mfma_f32_16x16x32_bf16(afr[ks], bfr[ks][nt], acc[nt], 0, 0, 0);

#pragma unroll
        for (int nt = 0; nt < 4; ++nt) {
            int cc = nt * 16 + m;
            float bl = bias[cc];
#pragma unroll
            for (int r = 0; r < 4; ++r) {
                int rr = row0 + q * 4 + r;
                h0b[(size_t)rr * 64 + cc] = f2bf(acc[nt][r] + bl);
            }
        }
        return;
    }
    if (b >= NBIN_BLOCKS) {
        int n = (b - NBIN_BLOCKS) * 256 + t;
        if (n >= N_NODES) return;
        int bb = batch[n];
        int prev = (n == 0) ? -1 : batch[n - 1];
        for (int g = prev + 1; g <= bb; ++g) gbound[g] = n;
        if (n == N_NODES - 1) {
            for (int g = bb + 1; g <= NGRAPH; ++g) gbound[g] = N_NODES;
        }
        return;
    }
    // ---------------- coalesced LDS-staged binning --------------------------
    for (int i = t; i < NBUCK; i += 256) lcount[i] = 0;
    __syncthreads();
    int base = b * EPB;
    unsigned rec[8]; int bp[8];
#pragma unroll
    for (int k = 0; k < 8; ++k) {
        int e = base + k * 256 + t;
        if (e < N_EDGES) {
            int r = row[e], c = col[e];
            int bk = r >> 9;
            int pos = atomicAdd(&lcount[bk], 1);       // rank within (block,bucket)
            rec[k] = ((unsigned)(r & 511) << 17) | (unsigned)c;
            bp[k] = (bk << 16) | pos;
        } else bp[k] = -1;
    }
    __syncthreads();
    // reserve global space + exclusive scan of block-local counts
    int v = (t < NBUCK) ? lcount[t] : 0;
    if (t < NBUCK) lbase[t] = (v > 0) ? atomicAdd(&gcursor[t], v) : 0;
    sc[t] = v; __syncthreads();
    for (int off = 1; off < 256; off <<= 1) {
        int u = (t >= off) ? sc[t - off] : 0;
        __syncthreads();
        sc[t] += u;
        __syncthreads();
    }
    int excl = sc[t] - v;
    if (t < NBUCK) {
        sexcl[t] = excl;
        lbase[t] = t * BUCKCAP + lbase[t] - excl;      // folded: dest = lbase[b] + slot
    }
    __syncthreads();
    // bucket-sort records into LDS staging
#pragma unroll
    for (int k = 0; k < 8; ++k) {
        if (bp[k] >= 0) {
            int bk = bp[k] >> 16, pos = bp[k] & 0xffff;
            int slot = sexcl[bk] + pos;
            staged[slot] = rec[k];
            sdelta[slot] = lbase[bk];
        }
    }
    __syncthreads();
    // coalesced copy-out: consecutive slots -> consecutive slab addrs per run
    int total = sc[255];
    for (int i = t; i < total; i += 256)
        slab[sdelta[i] + i] = staged[i];
}

// ---- K2: per-bucket CSR build (PAD-16) + fused h0s = fp8(h0b * dinv) -------
__global__ __launch_bounds__(256) void k_build_scale(const unsigned* __restrict__ slab,
        const int* __restrict__ gcursor,
        int* __restrict__ start, int* __restrict__ counts, float* __restrict__ dinv,
        unsigned* __restrict__ csr4,
        const ushort_t* __restrict__ h0b, unsigned char* __restrict__ h0s) {
    __shared__ int ncount[BUCKN];
    __shared__ int nstart[BUCKN];
    __shared__ int sc[256];
    __shared__ float sdv[BUCKN];
    int b = blockIdx.x, t = threadIdx.x;
    int cnt = gcursor[b];
    int ebase = b * WINCAP;
    int node0 = b * BUCKN;
    int nn = min(BUCKN, N_NODES - node0);
    for (int i = t; i < nn; i += 256) ncount[i] = 0;
    __syncthreads();
    const unsigned* sl = slab + (size_t)b * BUCKCAP;
    for (int i = t; i < cnt; i += 256)
        atomicAdd(&ncount[sl[i] >> 17], 1);
    __syncthreads();
    int c0 = (2 * t < nn) ? ncount[2 * t] : 0;
    int c1 = (2 * t + 1 < nn) ? ncount[2 * t + 1] : 0;
    int p0 = (c0 + 15) & ~15, p1 = (c1 + 15) & ~15;   // pad to 16 -> 1-round hop
    int ps = p0 + p1;
    sc[t] = ps; __syncthreads();
    for (int off = 1; off < 256; off <<= 1) {
        int v = (t >= off) ? sc[t - off] : 0;
        __syncthreads();
        sc[t] += v;
        __syncthreads();
    }
    int ex = sc[t] - ps;
    if (2 * t < nn) nstart[2 * t] = ex;
    if (2 * t + 1 < nn) nstart[2 * t + 1] = ex + p0;
    __syncthreads();
    for (int i = t; i < nn; i += 256) {
        int node = node0 + i;
        int c = ncount[i];
        int pc = (c + 15) & ~15;
        int st = ebase + nstart[i];
        start[node] = st;
        counts[node] = pc;                        // PADDED count for the hop
        float dv = rsqrtf((float)(c + 1));        // true degree for normalization
        dinv[node] = dv;
        sdv[i] = dv;
        for (int k = c; k < pc; ++k) csr4[st + k] = DUMMY;
    }
    __syncthreads();
    for (int i = t; i < cnt; i += 256) {
        unsigned r = sl[i];
        int pos = atomicAdd(&nstart[r >> 17], 1);
        csr4[ebase + pos] = r & 0x1ffffu;
    }
    // ---- fused scale: h0s[node][:] = fp8(h0b[node][:] * dinv[node]) --------
    const uint4* hp = (const uint4*)h0b;          // 16B = 8 bf16 per chunk
    uint2* op = (uint2*)h0s;                      // 8B  = 8 fp8 per chunk
    int nch = nn * 8;                             // 8 chunks per 64-feat row
    for (int i = t; i < nch; i += 256) {
        float dv = sdv[i >> 3];
        uint4 vch = hp[(size_t)node0 * 8 + i];
        ushort_t s0 = f32_fp8x2(bf_lo(vch.x) * dv, bf_hi(vch.x) * dv);
        ushort_t s1 = f32_fp8x2(bf_lo(vch.y) * dv, bf_hi(vch.y) * dv);
        ushort_t s2 = f32_fp8x2(bf_lo(vch.z) * dv, bf_hi(vch.z) * dv);
        ushort_t s3 = f32_fp8x2(bf_lo(vch.w) * dv, bf_hi(vch.w) * dv);
        uint2 o;
        o.x = (unsigned)s0 | ((unsigned)s1 << 16);
        o.y = (unsigned)s2 | ((unsigned)s3 << 16);
        op[(size_t)node0 * 8 + i] = o;
    }
    if (b == 0 && t < 16) ((unsigned*)(h0s + (size_t)N_NODES * 64))[t] = 0;  // dummy row
}

// ---- hop inner sum: 16 lanes/node (4 nodes/wave), dword fp8 gathers --------
// lane l (0..15) handles features 4l..4l+3 (one dword = 4 fp8).
// PAD-16 CSR: typical node = ONE dependent round {4 uint4 loads || 16 gathers}.
// Dummy pads gather the zeroed row at hs[N_NODES] (one L1-hot line).
__device__ __forceinline__ void hop_sum4(int node, int l,
        const unsigned* __restrict__ hs_in, const int* __restrict__ start,
        const int* __restrict__ counts, const unsigned* __restrict__ csr4,
        float& a0, float& a1, float& a2, float& a3) {
    unsigned su = hs_in[node * 16 + l];            // self-loop term (hs form)
    floatx2 slo = fp8x2_lo(su), shi = fp8x2_hi(su);
    a0 = slo.x; a1 = slo.y; a2 = shi.x; a3 = shi.y;
    int st = start[node], cnt = counts[node];      // cnt % 16 == 0, st 16B-aligned
    for (int j = 0; j < cnt; j += 16) {
        const uint4* cp = (const uint4*)(csr4 + st + j);
        uint4 g0 = cp[0];                          // 4 independent CSR loads
        uint4 g1 = cp[1];
        uint4 g2 = cp[2];
        uint4 g3 = cp[3];
        unsigned w0  = hs_in[g0.x * 16 + l];       // 16 independent gathers
        unsigned w1  = hs_in[g0.y * 16 + l];
        unsigned w2  = hs_in[g0.z * 16 + l];
        unsigned w3  = hs_in[g0.w * 16 + l];
        unsigned w4  = hs_in[g1.x * 16 + l];
        unsigned w5  = hs_in[g1.y * 16 + l];
        unsigned w6  = hs_in[g1.z * 16 + l];
        unsigned w7  = hs_in[g1.w * 16 + l];
        unsigned w8  = hs_in[g2.x * 16 + l];
        unsigned w9  = hs_in[g2.y * 16 + l];
        unsigned w10 = hs_in[g2.z * 16 + l];
        unsigned w11 = hs_in[g2.w * 16 + l];
        unsigned w12 = hs_in[g3.x * 16 + l];
        unsigned w13 = hs_in[g3.y * 16 + l];
        unsigned w14 = hs_in[g3.z * 16 + l];
        unsigned w15 = hs_in[g3.w * 16 + l];
        float s0 = 0.f, s1 = 0.f, s2 = 0.f, s3 = 0.f;
        unsigned wv[16] = {w0, w1, w2, w3, w4, w5, w6, w7,
                           w8, w9, w10, w11, w12, w13, w14, w15};
#pragma unroll
        for (int k = 0; k < 16; ++k) {
            floatx2 lo = fp8x2_lo(wv[k]), hi = fp8x2_hi(wv[k]);
            s0 += lo.x; s1 += lo.y; s2 += hi.x; s3 += hi.y;
        }
        a0 += s0; a1 += s1; a2 += s2; a3 += s3;
    }
}

// intermediate hop: residual from hs0 (fp8), writes fp8 hs_out (dword/lane):
//   hs_{k+1} = dinv * h_{k+1} = 0.5*di^2*S + 0.5*hs0
__global__ void k_hop(const unsigned* __restrict__ hs_in, const unsigned* __restrict__ hs0,
                      const float* __restrict__ dinv, const int* __restrict__ start,
                      const int* __restrict__ counts, const unsigned* __restrict__ csr4,
                      unsigned* __restrict__ hs_out) {
    int node = blockIdx.x * 16 + ((int)threadIdx.x >> 4);   // N_NODES % 16 == 0
    int l = threadIdx.x & 15;
    float a0, a1, a2, a3;
    hop_sum4(node, l, hs_in, start, counts, csr4, a0, a1, a2, a3);
    float di = dinv[node];
    float c = 0.5f * di * di;
    unsigned ru = hs0[node * 16 + l];
    floatx2 rlo = fp8x2_lo(ru), rhi = fp8x2_hi(ru);
    ushort_t lo = f32_fp8x2(c * a0 + 0.5f * rlo.x, c * a1 + 0.5f * rlo.y);
    ushort_t hi = f32_fp8x2(c * a2 + 0.5f * rhi.x, c * a3 + 0.5f * rhi.y);
    hs_out[node * 16 + l] = (unsigned)lo | ((unsigned)hi << 16);
    if (blockIdx.x == 0 && threadIdx.x < 16)
        hs_out[N_NODES * 16 + threadIdx.x] = 0;             // dummy row = 0
}

// final hop: bf16 h out (relu, residual from bf16 h0b) + attention gate
__global__ void k_hop_final(const unsigned* __restrict__ hs_in, const uint2* __restrict__ h0b2,
                            const float* __restrict__ dinv, const int* __restrict__ start,
                            const int* __restrict__ counts, const unsigned* __restrict__ csr4,
                            const float* __restrict__ w_att, const float* __restrict__ b_att,
                            uint2* __restrict__ h_out2, float* __restrict__ v_raw) {
    int node = blockIdx.x * 16 + ((int)threadIdx.x >> 4);
    int l = threadIdx.x & 15;
    float a0, a1, a2, a3;
    hop_sum4(node, l, hs_in, start, counts, csr4, a0, a1, a2, a3);
    float cdi = 0.5f * dinv[node];
    uint2 u = h0b2[node * 16 + l];
    float h0v = fmaxf(cdi * a0 + 0.5f * bf_lo(u.x), 0.f);
    float h1v = fmaxf(cdi * a1 + 0.5f * bf_hi(u.x), 0.f);
    float h2v = fmaxf(cdi * a2 + 0.5f * bf_lo(u.y), 0.f);
    float h3v = fmaxf(cdi * a3 + 0.5f * bf_hi(u.y), 0.f);
    uint2 o; o.x = pack2(h1v, h0v); o.y = pack2(h3v, h2v);
    h_out2[node * 16 + l] = o;
    float4 wa = *(const float4*)(w_att + 4 * l);
    float pp = (h0v * wa.x + h1v * wa.y) + (h2v * wa.z + h3v * wa.w);
#pragma unroll
    for (int off = 8; off >= 1; off >>= 1) pp += __shfl_xor(pp, off, 64);
    if (l == 0) {
        v_raw[node] = 1.f / (1.f + expf(-(pp + b_att[0])));
    }
}

// ---------------- readout + MLP head, one block per graph ----------------
__global__ void k_readout_mlp(const ushort_t* __restrict__ hb, const float* __restrict__ v_raw,
        const int* __restrict__ gbound,
        const float* __restrict__ W1, const float* __restrict__ b1,
        const float* __restrict__ W2, const float* __restrict__ b2,
        const float* __restrict__ W3, const float* __restrict__ b3,
        float* __restrict__ out) {
    int g = blockIdx.x, t = threadIdx.x;
    int s = gbound[g], e = gbound[g + 1];
    __shared__ float red[256];

    float m = -3.402823466e38f;
    for (int n = s + t; n < e; n += 256) m = fmaxf(m, v_raw[n]);
    red[t] = m; __syncthreads();
    for (int off = 128; off >= 1; off >>= 1) {
        if (t < off) red[t] = fmaxf(red[t], red[t + off]);
        __syncthreads();
    }
    float vmax = red[0]; __syncthreads();

    float ss = 0.f;
    for (int n = s + t; n < e; n += 256) ss += expf(v_raw[n] - vmax);
    red[t] = ss; __syncthreads();
    for (int off = 128; off >= 1; off >>= 1) {
        if (t < off) red[t] += red[t + off];
        __syncthreads();
    }
    float inv = 1.f / (red[0] + 1e-16f);
    __syncthreads();

    int wv = t >> 6, lane = t & 63;
    float gm = -3.402823466e38f, gs = 0.f;
    for (int n = s + wv; n < e; n += 4) {
        float hv = bf2f(hb[(size_t)n * 64 + lane]);
        float vn = expf(v_raw[n] - vmax) * inv;
        gm = fmaxf(gm, hv);
        gs += vn * hv;
    }
    __shared__ float pm[4][64], ps[4][64];
    pm[wv][lane] = gm; ps[wv][lane] = gs;
    __syncthreads();

    __shared__ float z[128];
    if (t < 64) {
        z[t] = fmaxf(fmaxf(pm[0][t], pm[1][t]), fmaxf(pm[2][t], pm[3][t]));
        z[64 + t] = ps[0][t] + ps[1][t] + ps[2][t] + ps[3][t];
    }
    __syncthreads();

    __shared__ float z1[64];
    if (t < 64) {
        float a = b1[t];
#pragma unroll 8
        for (int k = 0; k < 128; ++k) a += z[k] * W1[k * 64 + t];
        z1[t] = fmaxf(a, 0.f);
    }
    __syncthreads();
    __shared__ float z2[32];
    if (t < 32) {
        float a = b2[t];
#pragma unroll 8
        for (int k = 0; k < 64; ++k) a += z1[k] * W2[k * 32 + t];
        z2[t] = fmaxf(a, 0.f);
    }
    __syncthreads();
    __shared__ float z3[8];
    if (t < 8) {
        float a = b3[t];
#pragma unroll
        for (int k = 0; k < 32; ++k) a += z2[k] * W3[k * 8 + t];
        z3[t] = a;
    }
    __syncthreads();
    if (t == 0) {
        float mx = z3[0];
#pragma unroll
        for (int j = 1; j < 8; ++j) mx = fmaxf(mx, z3[j]);
        float se = 0.f;
#pragma unroll
        for (int j = 0; j < 8; ++j) se += expf(z3[j] - mx);
        float lse = mx + logf(se);
#pragma unroll
        for (int j = 0; j < 8; ++j) out[g * 8 + j] = z3[j] - lse;
    }
}

extern "C" void kernel_launch(void* const* d_in, const int* in_sizes, int n_in,
                              void* d_out, int out_size, void* d_ws, size_t ws_size,
                              hipStream_t stream) {
    const float* x     = (const float*)d_in[0];
    const int*   edge  = (const int*)d_in[1];
    const int*   row   = edge;
    const int*   col   = edge + N_EDGES;
    const int*   batch = (const int*)d_in[2];
    const float* W_sgc = (const float*)d_in[3];
    const float* b_sgc = (const float*)d_in[4];
    const float* w_att = (const float*)d_in[5];
    const float* b_att = (const float*)d_in[6];
    const float* W1    = (const float*)d_in[7];
    const float* b1    = (const float*)d_in[8];
    const float* W2    = (const float*)d_in[9];
    const float* b2    = (const float*)d_in[10];
    const float* W3    = (const float*)d_in[11];
    const float* b3    = (const float*)d_in[12];
    float* out = (float*)d_out;

    char* p = (char*)d_ws;
    auto alloc = [&](size_t bytes) {
        char* r = p;
        p += (bytes + 255) & ~(size_t)255;
        return r;
    };
    int*      gcursor = (int*)alloc((size_t)NBUCK * 4);          // zeroed below
    int*      gbound  = (int*)alloc((size_t)(NGRAPH + 1) * 4);
    int*      start   = (int*)alloc((size_t)N_NODES * 4);
    int*      counts  = (int*)alloc((size_t)N_NODES * 4);
    float*    dinv    = (float*)alloc((size_t)N_NODES * 4);
    float*    vraw    = (float*)alloc((size_t)N_NODES * 4);
    ushort_t* h0b     = (ushort_t*)alloc((size_t)N_NODES * 64 * 2);          // bf16
    unsigned char* h0s = (unsigned char*)alloc((size_t)(N_NODES + 1) * 64);  // fp8
    ushort_t* hAs     = (ushort_t*)alloc((size_t)(N_NODES + 1) * 32 * 2);    // fp8
    ushort_t* hBs     = (ushort_t*)alloc((size_t)(N_NODES + 1) * 32 * 2);    // fp8
    ushort_t* hfin    = (ushort_t*)alloc((size_t)N_NODES * 64 * 2);          // bf16 final h
    unsigned* csr4    = (unsigned*)alloc(((size_t)NBUCK * WINCAP + 64) * 4); // fixed windows
    unsigned* slab    = (unsigned*)alloc((size_t)NBUCK * BUCKCAP * 4);

    hipMemsetAsync(gcursor, 0, (size_t)NBUCK * 4, stream);

    k_bin_bounds_h0<<<NBIN_BLOCKS + NBOUND_BLOCKS + H0_BLOCKS, 256, 0, stream>>>(
        row, col, gcursor, slab, batch, gbound, x, W_sgc, b_sgc, h0b);
    k_build_scale<<<NBUCK, 256, 0, stream>>>(slab, gcursor, start, counts, dinv, csr4,
                                             h0b, (unsigned char*)h0s);
    k_hop<<<N_NODES / 16, 256, 0, stream>>>((const unsigned*)h0s, (const unsigned*)h0s,
                                            dinv, start, counts, csr4, (unsigned*)hAs);
    k_hop<<<N_NODES / 16, 256, 0, stream>>>((const unsigned*)hAs, (const unsigned*)h0s,
                                            dinv, start, counts, csr4, (unsigned*)hBs);
    k_hop_final<<<N_NODES / 16, 256, 0, stream>>>((const unsigned*)hBs, (const uint2*)h0b,
                                                  dinv, start, counts, csr4,
                                                  w_att, b_att, (uint2*)hfin, vraw);
    k_readout_mlp<<<NGRAPH, 256, 0, stream>>>(hfin, vraw, gbound,
                                              W1, b1, W2, b2, W3, b3, out);
}

// Round 11
// 197.218 us; speedup vs baseline: 1.5700x; 1.1246x over previous
//
#include <hip/hip_runtime.h>
#include <math.h>

#define N_NODES 100000
#define N_EDGES 1000000
#define NGRAPH 256

#define NBUCK 196          // ceil(100000 / 512)
#define BUCKN 512
#define BUCKCAP 8192       // max raw edges/bucket (mean ~5120, ~40 sigma margin)
#define EPB 4096           // edges per bin block (16/thread)
#define NBIN_BLOCKS ((N_EDGES + EPB - 1) / EPB)          // 245
#define NBOUND_BLOCKS ((N_NODES + 255) / 256)            // 391
#define WINCAP 10240       // fixed csr window per bucket (pad16 mean ~8400, 3.5s ~8620)
#define DUMMY ((unsigned)N_NODES)   // pad col -> node with hs == 0
#define H0_BLOCKS ((N_NODES / 16 + 3) / 4)               // 1563

typedef unsigned short ushort_t;
typedef __attribute__((ext_vector_type(2))) float floatx2;

__device__ __forceinline__ ushort_t f2bf(float f) {   // round-to-nearest-even
    unsigned u = __float_as_uint(f);
    u += 0x7fffu + ((u >> 16) & 1u);
    return (ushort_t)(u >> 16);
}
__device__ __forceinline__ float bf2f(ushort_t u) {
    return __uint_as_float(((unsigned)u) << 16);
}
__device__ __forceinline__ float bf_lo(unsigned u) {
    return __uint_as_float(u << 16);
}
__device__ __forceinline__ float bf_hi(unsigned u) {
    return __uint_as_float(u & 0xffff0000u);
}
__device__ __forceinline__ unsigned pack2(float hi, float lo) {
    return ((unsigned)f2bf(hi) << 16) | (unsigned)f2bf(lo);
}
// fp8 e4m3 (OCP) HW converts, gfx950
__device__ __forceinline__ floatx2 fp8x2_lo(unsigned u) {       // bytes 0,1
    return __builtin_amdgcn_cvt_pk_f32_fp8(u, false);
}
__device__ __forceinline__ floatx2 fp8x2_hi(unsigned u) {       // bytes 2,3
    return __builtin_amdgcn_cvt_pk_f32_fp8(u, true);
}
__device__ __forceinline__ ushort_t f32_fp8x2(float a, float b) {
    return (ushort_t)(__builtin_amdgcn_cvt_pk_fp8_f32(a, b, 0u, false) & 0xffffu);
}

using frag_ab = __attribute__((ext_vector_type(8))) short;
using frag_cd = __attribute__((ext_vector_type(4))) float;

// ---- K1: blocks [0,245) bin (coalesced staging); [245,636) graph bounds;
//          [636,2199) h0 = x@W+b in bf16 (h0b only) ------------------------
__global__ __launch_bounds__(256) void k_bin_bounds_h0(const int* __restrict__ row,
        const int* __restrict__ col, int* __restrict__ gcursor,
        unsigned* __restrict__ slab,
        const int* __restrict__ batch, int* __restrict__ gbound,
        const float* __restrict__ x, const float* __restrict__ W,
        const float* __restrict__ bias, ushort_t* __restrict__ h0b) {
    __shared__ int lcount[NBUCK];
    __shared__ int lbase[NBUCK];       // reserve, then folded dest base
    __shared__ int sexcl[NBUCK];       // block-local exclusive scan
    __shared__ int sc[256];
    __shared__ unsigned staged[EPB];
    __shared__ int sdelta[EPB];
    int t = threadIdx.x;
    int b = blockIdx.x;
    if (b >= NBIN_BLOCKS + NBOUND_BLOCKS) {
        // ---------------- h0 = x @ W_sgc + b_sgc (bf16 only) ----------------
        int wid = ((b - NBIN_BLOCKS - NBOUND_BLOCKS) * 256 + t) >> 6;
        if (wid >= N_NODES / 16) return;
        int lane = t & 63;
        int row0 = wid * 16;
        int m = lane & 15, q = lane >> 4;

        frag_ab bfr[2][4];
#pragma unroll
        for (int ks = 0; ks < 2; ++ks)
#pragma unroll
            for (int nt = 0; nt < 4; ++nt)
#pragma unroll
                for (int j = 0; j < 8; ++j)
                    bfr[ks][nt][j] = (short)f2bf(W[(ks * 32 + q * 8 + j) * 64 + nt * 16 + m]);

        frag_ab afr[2];
#pragma unroll
        for (int ks = 0; ks < 2; ++ks) {
            const float4* xp = (const float4*)(x + (size_t)(row0 + m) * 64 + ks * 32 + q * 8);
            float4 v0 = xp[0], v1 = xp[1];
            afr[ks][0] = (short)f2bf(v0.x); afr[ks][1] = (short)f2bf(v0.y);
            afr[ks][2] = (short)f2bf(v0.z); afr[ks][3] = (short)f2bf(v0.w);
            afr[ks][4] = (short)f2bf(v1.x); afr[ks][5] = (short)f2bf(v1.y);
            afr[ks][6] = (short)f2bf(v1.z); afr[ks][7] = (short)f2bf(v1.w);
        }

        frag_cd acc[4];
#pragma unroll
        for (int nt = 0; nt < 4; ++nt) acc[nt] = (frag_cd){0.f, 0.f, 0.f, 0.f};
#pragma unroll
        for (int ks = 0; ks < 2; ++ks)
#pragma unroll
            for (int nt = 0; nt < 4; ++nt)
                acc[nt] = __builtin_amdgcn_mfma_f32_16x16x32_bf16(afr[ks], bfr[ks][nt], acc[nt], 0, 0, 0);

#pragma unroll
        for (int nt = 0; nt < 4; ++nt) {
            int cc = nt * 16 + m;
            float bl = bias[cc];
#pragma unroll
            for (int r = 0; r < 4; ++r) {
                int rr = row0 + q * 4 + r;
                h0b[(size_t)rr * 64 + cc] = f2bf(acc[nt][r] + bl);
            }
        }
        return;
    }
    if (b >= NBIN_BLOCKS) {
        int n = (b - NBIN_BLOCKS) * 256 + t;
        if (n >= N_NODES) return;
        int bb = batch[n];
        int prev = (n == 0) ? -1 : batch[n - 1];
        for (int g = prev + 1; g <= bb; ++g) gbound[g] = n;
        if (n == N_NODES - 1) {
            for (int g = bb + 1; g <= NGRAPH; ++g) gbound[g] = N_NODES;
        }
        return;
    }
    // ---------------- coalesced LDS-staged binning --------------------------
    for (int i = t; i < NBUCK; i += 256) lcount[i] = 0;
    __syncthreads();
    int base = b * EPB;
    unsigned rec[16]; int bp[16];
#pragma unroll
    for (int k = 0; k < 16; ++k) {
        int e = base + k * 256 + t;
        if (e < N_EDGES) {
            int r = row[e], c = col[e];
            int bk = r >> 9;
            int pos = atomicAdd(&lcount[bk], 1);       // rank within (block,bucket)
            rec[k] = ((unsigned)(r & 511) << 17) | (unsigned)c;
            bp[k] = (bk << 16) | pos;
        } else bp[k] = -1;
    }
    __syncthreads();
    // reserve global space + exclusive scan of block-local counts
    int v = (t < NBUCK) ? lcount[t] : 0;
    if (t < NBUCK) lbase[t] = (v > 0) ? atomicAdd(&gcursor[t], v) : 0;
    sc[t] = v; __syncthreads();
    for (int off = 1; off < 256; off <<= 1) {
        int u = (t >= off) ? sc[t - off] : 0;
        __syncthreads();
        sc[t] += u;
        __syncthreads();
    }
    int excl = sc[t] - v;
    if (t < NBUCK) {
        sexcl[t] = excl;
        lbase[t] = t * BUCKCAP + lbase[t] - excl;      // folded: dest = lbase[b] + slot
    }
    __syncthreads();
    // bucket-sort records into LDS staging
#pragma unroll
    for (int k = 0; k < 16; ++k) {
        if (bp[k] >= 0) {
            int bk = bp[k] >> 16, pos = bp[k] & 0xffff;
            int slot = sexcl[bk] + pos;
            staged[slot] = rec[k];
            sdelta[slot] = lbase[bk];
        }
    }
    __syncthreads();
    // coalesced copy-out: consecutive slots -> consecutive slab addrs per run
    int total = sc[255];
    for (int i = t; i < total; i += 256)
        slab[sdelta[i] + i] = staged[i];
}

// ---- K2: per-bucket CSR build (PAD-16) + fused h0s = fp8(h0b * dinv) -------
__global__ __launch_bounds__(256) void k_build_scale(const unsigned* __restrict__ slab,
        const int* __restrict__ gcursor,
        int* __restrict__ start, int* __restrict__ counts, float* __restrict__ dinv,
        unsigned* __restrict__ csr4,
        const ushort_t* __restrict__ h0b, unsigned char* __restrict__ h0s) {
    __shared__ int ncount[BUCKN];
    __shared__ int nstart[BUCKN];
    __shared__ int sc[256];
    __shared__ float sdv[BUCKN];
    int b = blockIdx.x, t = threadIdx.x;
    int cnt = gcursor[b];
    int ebase = b * WINCAP;
    int node0 = b * BUCKN;
    int nn = min(BUCKN, N_NODES - node0);
    for (int i = t; i < nn; i += 256) ncount[i] = 0;
    __syncthreads();
    const unsigned* sl = slab + (size_t)b * BUCKCAP;
    for (int i = t; i < cnt; i += 256)
        atomicAdd(&ncount[sl[i] >> 17], 1);
    __syncthreads();
    int c0 = (2 * t < nn) ? ncount[2 * t] : 0;
    int c1 = (2 * t + 1 < nn) ? ncount[2 * t + 1] : 0;
    int p0 = (c0 + 15) & ~15, p1 = (c1 + 15) & ~15;   // pad to 16 -> 1-round hop
    int ps = p0 + p1;
    sc[t] = ps; __syncthreads();
    for (int off = 1; off < 256; off <<= 1) {
        int v = (t >= off) ? sc[t - off] : 0;
        __syncthreads();
        sc[t] += v;
        __syncthreads();
    }
    int ex = sc[t] - ps;
    if (2 * t < nn) nstart[2 * t] = ex;
    if (2 * t + 1 < nn) nstart[2 * t + 1] = ex + p0;
    __syncthreads();
    for (int i = t; i < nn; i += 256) {
        int node = node0 + i;
        int c = ncount[i];
        int pc = (c + 15) & ~15;
        int st = ebase + nstart[i];
        start[node] = st;
        counts[node] = pc;                        // PADDED count for the hop
        float dv = rsqrtf((float)(c + 1));        // true degree for normalization
        dinv[node] = dv;
        sdv[i] = dv;
        for (int k = c; k < pc; ++k) csr4[st + k] = DUMMY;
    }
    __syncthreads();
    for (int i = t; i < cnt; i += 256) {
        unsigned r = sl[i];
        int pos = atomicAdd(&nstart[r >> 17], 1);
        csr4[ebase + pos] = r & 0x1ffffu;
    }
    // ---- fused scale: h0s[node][:] = fp8(h0b[node][:] * dinv[node]) --------
    const uint4* hp = (const uint4*)h0b;          // 16B = 8 bf16 per chunk
    uint2* op = (uint2*)h0s;                      // 8B  = 8 fp8 per chunk
    int nch = nn * 8;                             // 8 chunks per 64-feat row
    for (int i = t; i < nch; i += 256) {
        float dv = sdv[i >> 3];
        uint4 vch = hp[(size_t)node0 * 8 + i];
        ushort_t s0 = f32_fp8x2(bf_lo(vch.x) * dv, bf_hi(vch.x) * dv);
        ushort_t s1 = f32_fp8x2(bf_lo(vch.y) * dv, bf_hi(vch.y) * dv);
        ushort_t s2 = f32_fp8x2(bf_lo(vch.z) * dv, bf_hi(vch.z) * dv);
        ushort_t s3 = f32_fp8x2(bf_lo(vch.w) * dv, bf_hi(vch.w) * dv);
        uint2 o;
        o.x = (unsigned)s0 | ((unsigned)s1 << 16);
        o.y = (unsigned)s2 | ((unsigned)s3 << 16);
        op[(size_t)node0 * 8 + i] = o;
    }
    if (b == 0 && t < 16) ((unsigned*)(h0s + (size_t)N_NODES * 64))[t] = 0;  // dummy row
}

// ---- hop inner sum: 16 lanes/node (4 nodes/wave), dword fp8 gathers --------
// lane l (0..15) handles features 4l..4l+3 (one dword = 4 fp8).
// PAD-16 CSR: typical node = ONE dependent round {4 uint4 loads || 16 gathers}.
// Dummy pads gather the zeroed row at hs[N_NODES] (one L1-hot line).
__device__ __forceinline__ void hop_sum4(int node, int l,
        const unsigned* __restrict__ hs_in, const int* __restrict__ start,
        const int* __restrict__ counts, const unsigned* __restrict__ csr4,
        float& a0, float& a1, float& a2, float& a3) {
    unsigned su = hs_in[node * 16 + l];            // self-loop term (hs form)
    floatx2 slo = fp8x2_lo(su), shi = fp8x2_hi(su);
    a0 = slo.x; a1 = slo.y; a2 = shi.x; a3 = shi.y;
    int st = start[node], cnt = counts[node];      // cnt % 16 == 0, st 16B-aligned
    for (int j = 0; j < cnt; j += 16) {
        const uint4* cp = (const uint4*)(csr4 + st + j);
        uint4 g0 = cp[0];                          // 4 independent CSR loads
        uint4 g1 = cp[1];
        uint4 g2 = cp[2];
        uint4 g3 = cp[3];
        unsigned w0  = hs_in[g0.x * 16 + l];       // 16 independent gathers
        unsigned w1  = hs_in[g0.y * 16 + l];
        unsigned w2  = hs_in[g0.z * 16 + l];
        unsigned w3  = hs_in[g0.w * 16 + l];
        unsigned w4  = hs_in[g1.x * 16 + l];
        unsigned w5  = hs_in[g1.y * 16 + l];
        unsigned w6  = hs_in[g1.z * 16 + l];
        unsigned w7  = hs_in[g1.w * 16 + l];
        unsigned w8  = hs_in[g2.x * 16 + l];
        unsigned w9  = hs_in[g2.y * 16 + l];
        unsigned w10 = hs_in[g2.z * 16 + l];
        unsigned w11 = hs_in[g2.w * 16 + l];
        unsigned w12 = hs_in[g3.x * 16 + l];
        unsigned w13 = hs_in[g3.y * 16 + l];
        unsigned w14 = hs_in[g3.z * 16 + l];
        unsigned w15 = hs_in[g3.w * 16 + l];
        float s0 = 0.f, s1 = 0.f, s2 = 0.f, s3 = 0.f;
        unsigned wv[16] = {w0, w1, w2, w3, w4, w5, w6, w7,
                           w8, w9, w10, w11, w12, w13, w14, w15};
#pragma unroll
        for (int k = 0; k < 16; ++k) {
            floatx2 lo = fp8x2_lo(wv[k]), hi = fp8x2_hi(wv[k]);
            s0 += lo.x; s1 += lo.y; s2 += hi.x; s3 += hi.y;
        }
        a0 += s0; a1 += s1; a2 += s2; a3 += s3;
    }
}

// intermediate hop: residual from hs0 (fp8), writes fp8 hs_out (dword/lane):
//   hs_{k+1} = dinv * h_{k+1} = 0.5*di^2*S + 0.5*hs0
__global__ void k_hop(const unsigned* __restrict__ hs_in, const unsigned* __restrict__ hs0,
                      const float* __restrict__ dinv, const int* __restrict__ start,
                      const int* __restrict__ counts, const unsigned* __restrict__ csr4,
                      unsigned* __restrict__ hs_out) {
    int node = blockIdx.x * 16 + ((int)threadIdx.x >> 4);   // N_NODES % 16 == 0
    int l = threadIdx.x & 15;
    float a0, a1, a2, a3;
    hop_sum4(node, l, hs_in, start, counts, csr4, a0, a1, a2, a3);
    float di = dinv[node];
    float c = 0.5f * di * di;
    unsigned ru = hs0[node * 16 + l];
    floatx2 rlo = fp8x2_lo(ru), rhi = fp8x2_hi(ru);
    ushort_t lo = f32_fp8x2(c * a0 + 0.5f * rlo.x, c * a1 + 0.5f * rlo.y);
    ushort_t hi = f32_fp8x2(c * a2 + 0.5f * rhi.x, c * a3 + 0.5f * rhi.y);
    hs_out[node * 16 + l] = (unsigned)lo | ((unsigned)hi << 16);
    if (blockIdx.x == 0 && threadIdx.x < 16)
        hs_out[N_NODES * 16 + threadIdx.x] = 0;             // dummy row = 0
}

// final hop: bf16 h out (relu, residual from bf16 h0b) + attention gate
__global__ void k_hop_final(const unsigned* __restrict__ hs_in, const uint2* __restrict__ h0b2,
                            const float* __restrict__ dinv, const int* __restrict__ start,
                            const int* __restrict__ counts, const unsigned* __restrict__ csr4,
                            const float* __restrict__ w_att, const float* __restrict__ b_att,
                            uint2* __restrict__ h_out2, float* __restrict__ v_raw) {
    int node = blockIdx.x * 16 + ((int)threadIdx.x >> 4);
    int l = threadIdx.x & 15;
    float a0, a1, a2, a3;
    hop_sum4(node, l, hs_in, start, counts, csr4, a0, a1, a2, a3);
    float cdi = 0.5f * dinv[node];
    uint2 u = h0b2[node * 16 + l];
    float h0v = fmaxf(cdi * a0 + 0.5f * bf_lo(u.x), 0.f);
    float h1v = fmaxf(cdi * a1 + 0.5f * bf_hi(u.x), 0.f);
    float h2v = fmaxf(cdi * a2 + 0.5f * bf_lo(u.y), 0.f);
    float h3v = fmaxf(cdi * a3 + 0.5f * bf_hi(u.y), 0.f);
    uint2 o; o.x = pack2(h1v, h0v); o.y = pack2(h3v, h2v);
    h_out2[node * 16 + l] = o;
    float4 wa = *(const float4*)(w_att + 4 * l);
    float pp = (h0v * wa.x + h1v * wa.y) + (h2v * wa.z + h3v * wa.w);
#pragma unroll
    for (int off = 8; off >= 1; off >>= 1) pp += __shfl_xor(pp, off, 64);
    if (l == 0) {
        v_raw[node] = 1.f / (1.f + expf(-(pp + b_att[0])));
    }
}

// ------- readout + MLP head: one 1024-thread block per graph (16 waves) -----
__global__ __launch_bounds__(1024) void k_readout_mlp(const ushort_t* __restrict__ hb,
        const float* __restrict__ v_raw, const int* __restrict__ gbound,
        const float* __restrict__ W1, const float* __restrict__ b1,
        const float* __restrict__ W2, const float* __restrict__ b2,
        const float* __restrict__ W3, const float* __restrict__ b3,
        float* __restrict__ out) {
    int g = blockIdx.x, t = threadIdx.x;
    int s = gbound[g], e = gbound[g + 1];
    __shared__ float red[1024];

    float m = -3.402823466e38f;
    for (int n = s + t; n < e; n += 1024) m = fmaxf(m, v_raw[n]);
    red[t] = m; __syncthreads();
    for (int off = 512; off >= 1; off >>= 1) {
        if (t < off) red[t] = fmaxf(red[t], red[t + off]);
        __syncthreads();
    }
    float vmax = red[0]; __syncthreads();

    float ss = 0.f;
    for (int n = s + t; n < e; n += 1024) ss += expf(v_raw[n] - vmax);
    red[t] = ss; __syncthreads();
    for (int off = 512; off >= 1; off >>= 1) {
        if (t < off) red[t] += red[t + off];
        __syncthreads();
    }
    float inv = 1.f / (red[0] + 1e-16f);
    __syncthreads();

    int wv = t >> 6, lane = t & 63;       // 16 waves, one node-row per wave/iter
    float gm = -3.402823466e38f, gs = 0.f;
    for (int n = s + wv; n < e; n += 16) {
        float hv = bf2f(hb[(size_t)n * 64 + lane]);
        float vn = expf(v_raw[n] - vmax) * inv;
        gm = fmaxf(gm, hv);
        gs += vn * hv;
    }
    __shared__ float pm[16][64], ps[16][64];
    pm[wv][lane] = gm; ps[wv][lane] = gs;
    __syncthreads();

    __shared__ float z[128];
    if (t < 64) {
        float zm = pm[0][t], zs = ps[0][t];
#pragma unroll
        for (int w = 1; w < 16; ++w) {
            zm = fmaxf(zm, pm[w][t]);
            zs += ps[w][t];
        }
        z[t] = zm;
        z[64 + t] = zs;
    }
    __syncthreads();

    __shared__ float z1[64];
    if (t < 64) {
        float a = b1[t];
#pragma unroll 8
        for (int k = 0; k < 128; ++k) a += z[k] * W1[k * 64 + t];
        z1[t] = fmaxf(a, 0.f);
    }
    __syncthreads();
    __shared__ float z2[32];
    if (t < 32) {
        float a = b2[t];
#pragma unroll 8
        for (int k = 0; k < 64; ++k) a += z1[k] * W2[k * 32 + t];
        z2[t] = fmaxf(a, 0.f);
    }
    __syncthreads();
    __shared__ float z3[8];
    if (t < 8) {
        float a = b3[t];
#pragma unroll
        for (int k = 0; k < 32; ++k) a += z2[k] * W3[k * 8 + t];
        z3[t] = a;
    }
    __syncthreads();
    if (t == 0) {
        float mx = z3[0];
#pragma unroll
        for (int j = 1; j < 8; ++j) mx = fmaxf(mx, z3[j]);
        float se = 0.f;
#pragma unroll
        for (int j = 0; j < 8; ++j) se += expf(z3[j] - mx);
        float lse = mx + logf(se);
#pragma unroll
        for (int j = 0; j < 8; ++j) out[g * 8 + j] = z3[j] - lse;
    }
}

extern "C" void kernel_launch(void* const* d_in, const int* in_sizes, int n_in,
                              void* d_out, int out_size, void* d_ws, size_t ws_size,
                              hipStream_t stream) {
    const float* x     = (const float*)d_in[0];
    const int*   edge  = (const int*)d_in[1];
    const int*   row   = edge;
    const int*   col   = edge + N_EDGES;
    const int*   batch = (const int*)d_in[2];
    const float* W_sgc = (const float*)d_in[3];
    const float* b_sgc = (const float*)d_in[4];
    const float* w_att = (const float*)d_in[5];
    const float* b_att = (const float*)d_in[6];
    const float* W1    = (const float*)d_in[7];
    const float* b1    = (const float*)d_in[8];
    const float* W2    = (const float*)d_in[9];
    const float* b2    = (const float*)d_in[10];
    const float* W3    = (const float*)d_in[11];
    const float* b3    = (const float*)d_in[12];
    float* out = (float*)d_out;

    char* p = (char*)d_ws;
    auto alloc = [&](size_t bytes) {
        char* r = p;
        p += (bytes + 255) & ~(size_t)255;
        return r;
    };
    int*      gcursor = (int*)alloc((size_t)NBUCK * 4);          // zeroed below
    int*      gbound  = (int*)alloc((size_t)(NGRAPH + 1) * 4);
    int*      start   = (int*)alloc((size_t)N_NODES * 4);
    int*      counts  = (int*)alloc((size_t)N_NODES * 4);
    float*    dinv    = (float*)alloc((size_t)N_NODES * 4);
    float*    vraw    = (float*)alloc((size_t)N_NODES * 4);
    ushort_t* h0b     = (ushort_t*)alloc((size_t)N_NODES * 64 * 2);          // bf16
    unsigned char* h0s = (unsigned char*)alloc((size_t)(N_NODES + 1) * 64);  // fp8
    ushort_t* hAs     = (ushort_t*)alloc((size_t)(N_NODES + 1) * 32 * 2);    // fp8
    ushort_t* hBs     = (ushort_t*)alloc((size_t)(N_NODES + 1) * 32 * 2);    // fp8
    ushort_t* hfin    = (ushort_t*)alloc((size_t)N_NODES * 64 * 2);          // bf16 final h
    unsigned* csr4    = (unsigned*)alloc(((size_t)NBUCK * WINCAP + 64) * 4); // fixed windows
    unsigned* slab    = (unsigned*)alloc((size_t)NBUCK * BUCKCAP * 4);

    hipMemsetAsync(gcursor, 0, (size_t)NBUCK * 4, stream);

    k_bin_bounds_h0<<<NBIN_BLOCKS + NBOUND_BLOCKS + H0_BLOCKS, 256, 0, stream>>>(
        row, col, gcursor, slab, batch, gbound, x, W_sgc, b_sgc, h0b);
    k_build_scale<<<NBUCK, 256, 0, stream>>>(slab, gcursor, start, counts, dinv, csr4,
                                             h0b, (unsigned char*)h0s);
    k_hop<<<N_NODES / 16, 256, 0, stream>>>((const unsigned*)h0s, (const unsigned*)h0s,
                                            dinv, start, counts, csr4, (unsigned*)hAs);
    k_hop<<<N_NODES / 16, 256, 0, stream>>>((const unsigned*)hAs, (const unsigned*)h0s,
                                            dinv, start, counts, csr4, (unsigned*)hBs);
    k_hop_final<<<N_NODES / 16, 256, 0, stream>>>((const unsigned*)hBs, (const uint2*)h0b,
                                                  dinv, start, counts, csr4,
                                                  w_att, b_att, (uint2*)hfin, vraw);
    k_readout_mlp<<<NGRAPH, 1024, 0, stream>>>(hfin, vraw, gbound,
                                               W1, b1, W2, b2, W3, b3, out);
}